// Round 8
// baseline (177.003 us; speedup 1.0000x reference)
//
#include <hip/hip_runtime.h>
#include <hip/hip_bf16.h>

// GAT layer on MI355X. Round 23: DECOMPOSE k_mega to attribute its stubborn
// ~50 us. History: k_mega ~45-52 us at occupancy 8.6% AND 27% -> occupancy
// isn't its limit; VALU 4%/MFMA 2%/HBM 14% -> nothing busy -> suspected
// serialized structure in the partition path (per-bucket device atomics +
// 16-barrier scans), unattributable inside the fused kernel. This round:
// (1) buckets back to 256-node (round-6 known-good: 21.5 KB LDS, coalesced
//     pairs chunks, k_aggslim 49.5); (2) k_mega split into k_prep (weights +
//     partition) and k_gemm (pure GEMM, ZERO LDS, own regalloc - combined
//     kernel got squeezed to 56 VGPR); (3) bcnt zero via hipMemsetAsync.
// Cost: +1 dispatch. Gain: per-path duration + VGPR visibility, and k_gemm
// freed from the partition's LDS/regalloc coupling. 4 dispatches.

#define NNODES 50000
#define NEDGES 800000
#define IN_F   256
#define HID    128
#define OUTF   64

#define PA_EPT   8
#define PA_EDGES (256 * PA_EPT)                          // 2048 edges/block
#define PA_NB    ((NEDGES + PA_EDGES - 1) / PA_EDGES)    // 391 blocks
#define NBKT     ((NNODES + 255) / 256)                  // 196 buckets (dst>>8)
#define BCAP     5120                                    // bucket capacity (lam=4082)
#define NSTRIP   (NNODES / 16)                           // 3125 strips
#define GB       ((NSTRIP + 3) / 4)                      // 782 gemm blocks

#define AGN      16                                      // nodes per agg block
#define AGSLOT   64                                      // per-node LDS slot cap (max deg ~45)
#define AGB      3136                                    // 8 * 392 agg blocks (>= 3125)

typedef unsigned short u16;
typedef unsigned long long u64;
typedef __bf16 bf16x8 __attribute__((ext_vector_type(8)));
typedef float  f32x4  __attribute__((ext_vector_type(4)));

__device__ __forceinline__ u16 f2b(float f) {
    union { float f; unsigned u; } v; v.f = f;
    unsigned u = v.u;
    return (u16)((u + 0x7fffu + ((u >> 16) & 1u)) >> 16);  // RNE fp32->bf16
}
__device__ __forceinline__ float b2f_lo(unsigned v) {
    union { unsigned u; float f; } c; c.u = (v & 0xffffu) << 16; return c.f;
}
__device__ __forceinline__ float b2f_hi(unsigned v) {
    union { unsigned u; float f; } c; c.u = v & 0xffff0000u; return c.f;
}
__device__ __forceinline__ float lrelu02_exp(float t) {
    t = t > 0.f ? t : 0.2f * t;                        // leaky_relu(0.2)
    return __expf(t);
}

// ---------------------------------------------------------------------------
// k_prep: blocks 0..15 pack W_gat, 16..19 pack W_lin, 20.. = edge partition
// into 196 bucket regions (round-6 partition, 21.5 KB LDS).
__global__ __launch_bounds__(256) void k_prep(
        const float* __restrict__ Wg, const float* __restrict__ Wl,
        u16* __restrict__ pWg, u16* __restrict__ pWl,
        const int* __restrict__ src, const int* __restrict__ dst,
        int* __restrict__ bcnt, u64* __restrict__ pairs) {
    __shared__ u64 smemU[21504 / 8];
    char* smem = (char*)smemU;
    int blk = blockIdx.x, tid = threadIdx.x;

    if (blk < 16) {
        int t = blk * 256 + tid;
        int lane = t & 63, tile = t >> 6;
        int nt = tile & 7, kt = tile >> 3;
        int col = lane & 15, quad = lane >> 4;
        int krow = kt * 32 + quad * 8;
        int ncol = nt * 16 + col;
#pragma unroll
        for (int j = 0; j < 8; j++) pWg[t * 8 + j] = f2b(Wg[(krow + j) * HID + ncol]);
        return;
    } else if (blk < 20) {
        int t = (blk - 16) * 256 + tid;
        int lane = t & 63, tile = t >> 6;
        int nt = tile & 3, kt = tile >> 2;
        int col = lane & 15, quad = lane >> 4;
        int o  = nt * 16 + col;
        int k0 = kt * 32 + quad * 8;
#pragma unroll
        for (int j = 0; j < 8; j++) pWl[t * 8 + j] = f2b(Wl[o * HID + k0 + j]);
        return;
    }

    // ---- edge partition path ----
    int* hist    = (int*)smem;                         // 256 ints (196 used)
    int* binbase = hist + 256;
    int* gbase   = binbase + 256;
    int* fill    = gbase + 256;
    int* stmp    = fill + 256;                         // 256 ints -> 5120 B
    u64* spair   = (u64*)(smem + 5120);                // 2048 * 8 = 16384 B

    int e0 = (blk - 20) * PA_EDGES;
    int cnt = NEDGES - e0; if (cnt > PA_EDGES) cnt = PA_EDGES;

    hist[tid] = 0; fill[tid] = 0;
    __syncthreads();

    int es[PA_EPT], ed[PA_EPT];
#pragma unroll
    for (int j = 0; j < PA_EPT; j++) {
        int idx = e0 + j * 256 + tid;
        if (idx < NEDGES) {
            es[j] = src[idx];
            ed[j] = dst[idx];
            atomicAdd(&hist[ed[j] >> 8], 1);
        } else ed[j] = -1;
    }
    __syncthreads();

    stmp[tid] = (tid < NBKT) ? hist[tid] : 0;
    __syncthreads();
#pragma unroll
    for (int ofs = 1; ofs < 256; ofs <<= 1) {
        int u = (tid >= ofs) ? stmp[tid - ofs] : 0;
        __syncthreads();
        stmp[tid] += u;
        __syncthreads();
    }
    if (tid < NBKT) {
        binbase[tid] = stmp[tid] - hist[tid];
        if (hist[tid] > 0)
            gbase[tid] = tid * BCAP + atomicAdd(&bcnt[tid], hist[tid]);
    }
    __syncthreads();

#pragma unroll
    for (int j = 0; j < PA_EPT; j++) {
        if (ed[j] >= 0) {
            int b = ed[j] >> 8;
            int r = atomicAdd(&fill[b], 1);
            int loc = binbase[b] + r;
            spair[loc] = ((u64)(unsigned)ed[j] << 32) | (unsigned)es[j];
        }
    }
    __syncthreads();

    for (int i = tid; i < cnt; i += 256) {
        u64 p = spair[i];
        int b = (int)(p >> 40);                        // dst>>8 from packed pair
        pairs[gbase[b] + (i - binbase[b])] = p;
    }
}

// ---------------------------------------------------------------------------
// k_gemm: pure feat GEMM (1 strip/wave, 16 hoisted x-loads, fused el/er
// epilogue). No LDS, own register allocation.
__global__ __launch_bounds__(256) void k_gemm(
        const float* __restrict__ x, const u16* __restrict__ pWg,
        const float* __restrict__ al_, const float* __restrict__ ar_,
        unsigned* __restrict__ feat2, float* __restrict__ el,
        float* __restrict__ er) {
    int blk = blockIdx.x, tid = threadIdx.x;
    int wave = tid >> 6, lane = tid & 63;
    int strip = blk * 4 + wave;
    if (strip >= NSTRIP) return;
    int m0 = strip * 16;
    int col = lane & 15, quad = lane >> 4;

    // hoist ALL x loads for this strip: 16 independent 16B loads/lane
    f32x4 xa[16];
    const float* xr = x + (size_t)(m0 + col) * IN_F + quad * 8;
#pragma unroll
    for (int kt = 0; kt < 8; kt++) {
        xa[2 * kt]     = *reinterpret_cast<const f32x4*>(xr + kt * 32);
        xa[2 * kt + 1] = *reinterpret_cast<const f32x4*>(xr + kt * 32 + 4);
    }
    bf16x8 av[8];
#pragma unroll
    for (int kt = 0; kt < 8; kt++)
#pragma unroll
        for (int j = 0; j < 4; j++) {
            av[kt][j]     = (__bf16)xa[2 * kt][j];
            av[kt][4 + j] = (__bf16)xa[2 * kt + 1][j];
        }

    f32x4 acc[8] = {};
#pragma unroll
    for (int kt = 0; kt < 8; kt++)
#pragma unroll
        for (int nt = 0; nt < 8; nt++) {
            bf16x8 b = *reinterpret_cast<const bf16x8*>(pWg + ((kt * 8 + nt) * 64 + lane) * 8);
            acc[nt] = __builtin_amdgcn_mfma_f32_16x16x32_bf16(av[kt], b, acc[nt], 0, 0, 0);
        }

    // epilogue: el/er dot products + bf16 feat store
    float pl[4] = {0, 0, 0, 0}, pr[4] = {0, 0, 0, 0};
#pragma unroll
    for (int nt = 0; nt < 8; nt++) {
        float alv = al_[nt * 16 + col], arv = ar_[nt * 16 + col];
#pragma unroll
        for (int reg = 0; reg < 4; reg++) {
            pl[reg] += acc[nt][reg] * alv;
            pr[reg] += acc[nt][reg] * arv;
        }
    }
#pragma unroll
    for (int m = 1; m < 16; m <<= 1)
#pragma unroll
        for (int reg = 0; reg < 4; reg++) {
            pl[reg] += __shfl_xor(pl[reg], m, 64);
            pr[reg] += __shfl_xor(pr[reg], m, 64);
        }
    if (col == 0) {
#pragma unroll
        for (int reg = 0; reg < 4; reg++) {
            el[m0 + quad * 4 + reg] = pl[reg];
            er[m0 + quad * 4 + reg] = pr[reg];
        }
    }
#pragma unroll
    for (int nt = 0; nt < 8; nt++)
#pragma unroll
        for (int reg = 0; reg < 4; reg++) {
            u16* fp = (u16*)feat2;
            fp[(size_t)(m0 + quad * 4 + reg) * HID + nt * 16 + col] = f2b(acc[nt][reg]);
        }
}

// ---------------------------------------------------------------------------
// k_aggslim: one block (256 thr) per 16 nodes (3136 blocks, XCD-swizzled so
// a coarse bucket's 16 blocks share one XCD L2). Phase A: stream the coarse
// bucket's pairs window, filter to the block's 16 nodes (1 compare / 8B),
// build 16x64-slot LDS lists with w = exp(lrelu02(el[s]+er[d])) inline.
// Phase B: 8-deep wave-per-node feat2 gather + inline denominator.
// Phase C: 16x64 MFMA output tile.
__global__ __launch_bounds__(256) void k_aggslim(const u64* __restrict__ pairs,
                                                 const int* __restrict__ bcnt,
                                                 const float* __restrict__ el,
                                                 const float* __restrict__ er,
                                                 const unsigned* __restrict__ feat2,
                                                 const float* __restrict__ bias,
                                                 const u16* __restrict__ pWl,
                                                 float* __restrict__ out) {
    __shared__ int   cnt_l[AGN];
    __shared__ float erl[AGN];
    __shared__ int   ssrc[AGN * AGSLOT];               // 4 KB
    __shared__ float swgt[AGN * AGSLOT];               // 4 KB
    __shared__ unsigned sg[AGN * 68];                  // 4.35 KB

    int tid = threadIdx.x;
    int wave = tid >> 6, lane = tid & 63;
    // XCD-bijective swizzle: 3136 = 8 * 392; bucket's 16 blocks -> one XCD.
    int logical = (blockIdx.x & 7) * 392 + (blockIdx.x >> 3);
    int nb = logical * AGN;
    if (nb >= NNODES) return;
    int cb = logical >> 4;                             // coarse 256-node bucket

    if (tid < AGN) {
        cnt_l[tid] = 0;
        erl[tid] = er[nb + tid];
    }
    __syncthreads();

    // ---- phase A: filter + attention weight + LDS list build ----
    int cntb = bcnt[cb];
    const u64* reg = pairs + (size_t)cb * BCAP;
    for (int i = tid; i < cntb; i += 256) {
        u64 p = reg[i];
        int d = (int)(unsigned)(p >> 32);
        unsigned dl = (unsigned)(d - nb);
        if (dl < (unsigned)AGN) {
            int s = (int)(unsigned)(p & 0xffffffffu);
            float w = lrelu02_exp(el[s] + erl[dl]);
            int slot = atomicAdd(&cnt_l[dl], 1);
            if (slot < AGSLOT) {
                ssrc[dl * AGSLOT + slot] = s;
                swgt[dl * AGSLOT + slot] = w;
            }
        }
    }
    __syncthreads();

    // ---- phase B: wave-per-node gather + normalize ----
    float bl = bias[lane * 2 + 0], bh = bias[lane * 2 + 1];
    for (int i = 0; i < 4; i++) {
        int dl = wave * 4 + i;
        int cnt = cnt_l[dl]; if (cnt > AGSLOT) cnt = AGSLOT;
        const int*   ep = ssrc + dl * AGSLOT;
        const float* wp = swgt + dl * AGSLOT;

        float p0 = 0.f, p1 = 0.f, q0 = 0.f, q1 = 0.f;
        float r0 = 0.f, r1 = 0.f, t0 = 0.f, t1 = 0.f;
        float u0 = 0.f, u1 = 0.f, x0 = 0.f, x1 = 0.f;
        float y0 = 0.f, y1 = 0.f, z0 = 0.f, z1 = 0.f;
        float dn = 0.f;
        int j = 0;
        for (; j + 8 <= cnt; j += 8) {
            int4 sa = *reinterpret_cast<const int4*>(ep + j);
            int4 sb = *reinterpret_cast<const int4*>(ep + j + 4);
            float4 wa = *reinterpret_cast<const float4*>(wp + j);
            float4 wb = *reinterpret_cast<const float4*>(wp + j + 4);
            unsigned v0 = feat2[(size_t)sa.x * 64 + lane];
            unsigned v1 = feat2[(size_t)sa.y * 64 + lane];
            unsigned v2 = feat2[(size_t)sa.z * 64 + lane];
            unsigned v3 = feat2[(size_t)sa.w * 64 + lane];
            unsigned v4 = feat2[(size_t)sb.x * 64 + lane];
            unsigned v5 = feat2[(size_t)sb.y * 64 + lane];
            unsigned v6 = feat2[(size_t)sb.z * 64 + lane];
            unsigned v7 = feat2[(size_t)sb.w * 64 + lane];
            p0 += wa.x * b2f_lo(v0); p1 += wa.x * b2f_hi(v0);
            q0 += wa.y * b2f_lo(v1); q1 += wa.y * b2f_hi(v1);
            r0 += wa.z * b2f_lo(v2); r1 += wa.z * b2f_hi(v2);
            t0 += wa.w * b2f_lo(v3); t1 += wa.w * b2f_hi(v3);
            u0 += wb.x * b2f_lo(v4); u1 += wb.x * b2f_hi(v4);
            x0 += wb.y * b2f_lo(v5); x1 += wb.y * b2f_hi(v5);
            y0 += wb.z * b2f_lo(v6); y1 += wb.z * b2f_hi(v6);
            z0 += wb.w * b2f_lo(v7); z1 += wb.w * b2f_hi(v7);
            dn += ((wa.x + wa.y) + (wa.z + wa.w)) + ((wb.x + wb.y) + (wb.z + wb.w));
        }
        if (j + 4 <= cnt) {
            int4 sa = *reinterpret_cast<const int4*>(ep + j);
            float4 wa = *reinterpret_cast<const float4*>(wp + j);
            unsigned v0 = feat2[(size_t)sa.x * 64 + lane];
            unsigned v1 = feat2[(size_t)sa.y * 64 + lane];
            unsigned v2 = feat2[(size_t)sa.z * 64 + lane];
            unsigned v3 = feat2[(size_t)sa.w * 64 + lane];
            p0 += wa.x * b2f_lo(v0); p1 += wa.x * b2f_hi(v0);
            q0 += wa.y * b2f_lo(v1); q1 += wa.y * b2f_hi(v1);
            r0 += wa.z * b2f_lo(v2); r1 += wa.z * b2f_hi(v2);
            t0 += wa.w * b2f_lo(v3); t1 += wa.w * b2f_hi(v3);
            dn += (wa.x + wa.y) + (wa.z + wa.w);
            j += 4;
        }
        for (; j < cnt; j++) {
            int s = ep[j];
            float w = wp[j];
            unsigned v = feat2[(size_t)s * 64 + lane];
            p0 += w * b2f_lo(v); p1 += w * b2f_hi(v);
            dn += w;
        }
        float a0 = ((p0 + q0) + (r0 + t0)) + ((u0 + x0) + (y0 + z0));
        float a1 = ((p1 + q1) + (r1 + t1)) + ((u1 + x1) + (y1 + z1));

        float inv = dn > 0.f ? 1.f / dn : 0.f;         // isolated node -> 0
        float g0 = a0 * inv + bl;
        float g1 = a1 * inv + bh;
        g0 = g0 > 0.f ? g0 : 0.01f * g0;               // leaky_relu(0.01)
        g1 = g1 > 0.f ? g1 : 0.01f * g1;
        sg[(wave * 4 + i) * 68 + lane] = (unsigned)f2b(g0) | ((unsigned)f2b(g1) << 16);
    }
    __syncthreads();

    // ---- phase C: 16x64 output GEMM ----
    int col = lane & 15, quad = lane >> 4;
    int nt = wave;
    f32x4 acc = {};
#pragma unroll
    for (int kt = 0; kt < 4; kt++) {
        bf16x8 a = *reinterpret_cast<const bf16x8*>(&sg[col * 68 + kt * 16 + quad * 4]);
        bf16x8 bf = *reinterpret_cast<const bf16x8*>(pWl + ((kt * 4 + nt) * 64 + lane) * 8);
        acc = __builtin_amdgcn_mfma_f32_16x16x32_bf16(a, bf, acc, 0, 0, 0);
    }
#pragma unroll
    for (int reg = 0; reg < 4; reg++)
        out[(size_t)(nb + quad * 4 + reg) * OUTF + nt * 16 + col] = acc[reg];
}

// ---------------------------------------------------------------------------
extern "C" void kernel_launch(void* const* d_in, const int* in_sizes, int n_in,
                              void* d_out, int out_size, void* d_ws, size_t ws_size,
                              hipStream_t stream) {
    const float* x      = (const float*)d_in[0];   // [50000,256] fp32
    const int*   src    = (const int*)d_in[1];     // [800000] int32
    const int*   dst    = (const int*)d_in[2];     // [800000] int32
    const float* Wg     = (const float*)d_in[3];   // [256,128] fp32
    const float* attn_l = (const float*)d_in[4];   // [128]
    const float* attn_r = (const float*)d_in[5];   // [128]
    const float* bias   = (const float*)d_in[6];   // [128]
    const float* Wl     = (const float*)d_in[7];   // [64,128] fp32
    float* out          = (float*)d_out;           // [50000,64] fp32

    char* ws = (char*)d_ws;
    size_t off = 0;
    auto alloc = [&](size_t b) { size_t r = off; off += (b + 255) & ~(size_t)255; return r; };
    size_t pwgOff  = alloc((size_t)8 * 8 * 64 * 8 * 2);     // 64 KB
    size_t pwlOff  = alloc((size_t)4 * 4 * 64 * 8 * 2);     // 16 KB
    size_t featOff = alloc((size_t)NNODES * HID * 2);       // 12.8 MB bf16 feat
    size_t elOff   = alloc((size_t)NNODES * 4);
    size_t erOff   = alloc((size_t)NNODES * 4);
    size_t pairOff = alloc((size_t)NBKT * BCAP * 8);        // 8.0 MB bucket regions
    size_t bcntOff = alloc((size_t)NBKT * 4);

    u16*      pWg   = (u16*)(ws + pwgOff);
    u16*      pWl   = (u16*)(ws + pwlOff);
    unsigned* feat2 = (unsigned*)(ws + featOff);
    float*    el    = (float*)(ws + elOff);
    float*    er    = (float*)(ws + erOff);
    u64*      pairs = (u64*)(ws + pairOff);
    int*      bcnt  = (int*)(ws + bcntOff);

    hipMemsetAsync(bcnt, 0, (size_t)NBKT * 4, stream);
    k_prep<<<20 + PA_NB, 256, 0, stream>>>(Wg, Wl, pWg, pWl, src, dst, bcnt, pairs);
    k_gemm<<<GB, 256, 0, stream>>>(x, pWg, attn_l, attn_r, feat2, el, er);
    k_aggslim<<<AGB, 256, 0, stream>>>(pairs, bcnt, el, er, feat2, bias,
                                       pWl, out);
}

// Round 9
// 168.509 us; speedup vs baseline: 1.0504x; 1.0504x over previous
//
#include <hip/hip_runtime.h>
#include <hip/hip_bf16.h>

// GAT layer on MI355X. Round 24: back to round-6 fused structure (best 165.1;
// round-8 split cost +12 us serialization, but proved k_prep/k_gemm < 49 and
// k_aggslim == 49 us stable). Attack k_aggslim's phase-A scan BYTES: the
// 16x-redundant window scan = 3136 x 4082 x 8B = 512 MB of L2 requests
// (~15 us of L2 BW) -- the redundancy tax is bytes, not VALU.
// (1) k_mega's partition scatter also emits dstb[] = d&255 (1 B/edge, same
//     index as pairs). ~5 MB partial-line writes on an 800 KB array.
// (2) k_aggslim phase A scans dstb as packed u32 (4 records/load, 64 MB of
//     L2 requests, 8x less); loads pairs[i] (4B src) only on match (1/16).
//     Tail guard idx<cntb short-circuits behind the range check.
// (3) phase B feat2 gather uses 32-bit base+voffset addressing.
// k_mega GEMM path / pack0 / phases B-C otherwise byte-identical to round 6.
// 3 dispatches.

#define NNODES 50000
#define NEDGES 800000
#define IN_F   256
#define HID    128
#define OUTF   64

#define PA_EPT   8
#define PA_EDGES (256 * PA_EPT)                          // 2048 edges/block
#define PA_NB    ((NEDGES + PA_EDGES - 1) / PA_EDGES)    // 391 blocks
#define NBKT     ((NNODES + 255) / 256)                  // 196 buckets (dst>>8)
#define BCAP     5120                                    // bucket capacity (lam=4082)
#define NSTRIP   (NNODES / 16)                           // 3125 strips
#define GB       ((NSTRIP + 3) / 4)                      // 782 gemm blocks

#define AGN      16                                      // nodes per agg block
#define AGSLOT   64                                      // per-node LDS slot cap (max deg ~45)
#define AGB      3136                                    // 8 * 392 agg blocks (>= 3125)

typedef unsigned short u16;
typedef unsigned char  u8;
typedef unsigned long long u64;
typedef __bf16 bf16x8 __attribute__((ext_vector_type(8)));
typedef float  f32x4  __attribute__((ext_vector_type(4)));

__device__ __forceinline__ u16 f2b(float f) {
    union { float f; unsigned u; } v; v.f = f;
    unsigned u = v.u;
    return (u16)((u + 0x7fffu + ((u >> 16) & 1u)) >> 16);  // RNE fp32->bf16
}
__device__ __forceinline__ float b2f_lo(unsigned v) {
    union { unsigned u; float f; } c; c.u = (v & 0xffffu) << 16; return c.f;
}
__device__ __forceinline__ float b2f_hi(unsigned v) {
    union { unsigned u; float f; } c; c.u = v & 0xffff0000u; return c.f;
}
__device__ __forceinline__ float lrelu02_exp(float t) {
    t = t > 0.f ? t : 0.2f * t;                        // leaky_relu(0.2)
    return __expf(t);
}

// ---------------------------------------------------------------------------
// pack0: blocks 0..15 pack W_gat, 16..19 pack W_lin, 20 zeroes bcnt.
__global__ __launch_bounds__(256) void pack0(const float* __restrict__ Wg,
                                             const float* __restrict__ Wl,
                                             u16* __restrict__ pWg,
                                             u16* __restrict__ pWl,
                                             int* __restrict__ bcnt) {
    int blk = blockIdx.x, tid = threadIdx.x;
    if (blk < 16) {
        int t = blk * 256 + tid;
        int lane = t & 63, tile = t >> 6;
        int nt = tile & 7, kt = tile >> 3;
        int col = lane & 15, quad = lane >> 4;
        int krow = kt * 32 + quad * 8;
        int ncol = nt * 16 + col;
#pragma unroll
        for (int j = 0; j < 8; j++) pWg[t * 8 + j] = f2b(Wg[(krow + j) * HID + ncol]);
    } else if (blk < 20) {
        int t = (blk - 16) * 256 + tid;
        int lane = t & 63, tile = t >> 6;
        int nt = tile & 3, kt = tile >> 2;
        int col = lane & 15, quad = lane >> 4;
        int o  = nt * 16 + col;
        int k0 = kt * 32 + quad * 8;
#pragma unroll
        for (int j = 0; j < 8; j++) pWl[t * 8 + j] = f2b(Wl[o * HID + k0 + j]);
    } else {
        if (tid < NBKT) bcnt[tid] = 0;
    }
}

// ---------------------------------------------------------------------------
// k_mega: blocks [0,GB) = feat GEMM (1 strip/wave, 16 hoisted x-loads,
// fused el/er epilogue); blocks [GB, GB+PA_NB) = edge partition into 196
// bucket regions (+ parallel dstb u8 stream). Paths run concurrently.
__global__ __launch_bounds__(256) void k_mega(
        const float* __restrict__ x, const u16* __restrict__ pWg,
        const float* __restrict__ al_, const float* __restrict__ ar_,
        unsigned* __restrict__ feat2, float* __restrict__ el, float* __restrict__ er,
        const int* __restrict__ src, const int* __restrict__ dst,
        int* __restrict__ bcnt, u64* __restrict__ pairs, u8* __restrict__ dstb) {
    __shared__ u64 smemU[21504 / 8];
    char* smem = (char*)smemU;
    int blk = blockIdx.x, tid = threadIdx.x;

    if (blk < GB) {
        // ---- feat GEMM path (no LDS use) ----
        int wave = tid >> 6, lane = tid & 63;
        int strip = blk * 4 + wave;
        if (strip >= NSTRIP) return;
        int m0 = strip * 16;
        int col = lane & 15, quad = lane >> 4;

        // hoist ALL x loads for this strip: 16 independent 16B loads/lane
        f32x4 xa[16];
        const float* xr = x + (size_t)(m0 + col) * IN_F + quad * 8;
#pragma unroll
        for (int kt = 0; kt < 8; kt++) {
            xa[2 * kt]     = *reinterpret_cast<const f32x4*>(xr + kt * 32);
            xa[2 * kt + 1] = *reinterpret_cast<const f32x4*>(xr + kt * 32 + 4);
        }
        bf16x8 av[8];
#pragma unroll
        for (int kt = 0; kt < 8; kt++)
#pragma unroll
            for (int j = 0; j < 4; j++) {
                av[kt][j]     = (__bf16)xa[2 * kt][j];
                av[kt][4 + j] = (__bf16)xa[2 * kt + 1][j];
            }

        f32x4 acc[8] = {};
#pragma unroll
        for (int kt = 0; kt < 8; kt++)
#pragma unroll
            for (int nt = 0; nt < 8; nt++) {
                bf16x8 b = *reinterpret_cast<const bf16x8*>(pWg + ((kt * 8 + nt) * 64 + lane) * 8);
                acc[nt] = __builtin_amdgcn_mfma_f32_16x16x32_bf16(av[kt], b, acc[nt], 0, 0, 0);
            }

        // epilogue: el/er dot products + bf16 feat store
        float pl[4] = {0, 0, 0, 0}, pr[4] = {0, 0, 0, 0};
#pragma unroll
        for (int nt = 0; nt < 8; nt++) {
            float alv = al_[nt * 16 + col], arv = ar_[nt * 16 + col];
#pragma unroll
            for (int reg = 0; reg < 4; reg++) {
                pl[reg] += acc[nt][reg] * alv;
                pr[reg] += acc[nt][reg] * arv;
            }
        }
#pragma unroll
        for (int m = 1; m < 16; m <<= 1)
#pragma unroll
            for (int reg = 0; reg < 4; reg++) {
                pl[reg] += __shfl_xor(pl[reg], m, 64);
                pr[reg] += __shfl_xor(pr[reg], m, 64);
            }
        if (col == 0) {
#pragma unroll
            for (int reg = 0; reg < 4; reg++) {
                el[m0 + quad * 4 + reg] = pl[reg];
                er[m0 + quad * 4 + reg] = pr[reg];
            }
        }
#pragma unroll
        for (int nt = 0; nt < 8; nt++)
#pragma unroll
            for (int reg = 0; reg < 4; reg++) {
                u16* fp = (u16*)feat2;
                fp[(size_t)(m0 + quad * 4 + reg) * HID + nt * 16 + col] = f2b(acc[nt][reg]);
            }
        return;
    }

    // ---- edge partition path ----
    int* hist    = (int*)smem;                         // 256 ints (196 used)
    int* binbase = hist + 256;
    int* gbase   = binbase + 256;
    int* fill    = gbase + 256;
    int* stmp    = fill + 256;                         // 256 ints -> 5120 B
    u64* spair   = (u64*)(smem + 5120);                // 2048 * 8 = 16384 B

    int e0 = (blk - GB) * PA_EDGES;
    int cnt = NEDGES - e0; if (cnt > PA_EDGES) cnt = PA_EDGES;

    hist[tid] = 0; fill[tid] = 0;
    __syncthreads();

    int es[PA_EPT], ed[PA_EPT];
#pragma unroll
    for (int j = 0; j < PA_EPT; j++) {
        int idx = e0 + j * 256 + tid;
        if (idx < NEDGES) {
            es[j] = src[idx];
            ed[j] = dst[idx];
            atomicAdd(&hist[ed[j] >> 8], 1);
        } else ed[j] = -1;
    }
    __syncthreads();

    stmp[tid] = (tid < NBKT) ? hist[tid] : 0;
    __syncthreads();
#pragma unroll
    for (int ofs = 1; ofs < 256; ofs <<= 1) {
        int u = (tid >= ofs) ? stmp[tid - ofs] : 0;
        __syncthreads();
        stmp[tid] += u;
        __syncthreads();
    }
    if (tid < NBKT) {
        binbase[tid] = stmp[tid] - hist[tid];
        if (hist[tid] > 0)
            gbase[tid] = tid * BCAP + atomicAdd(&bcnt[tid], hist[tid]);
    }
    __syncthreads();

#pragma unroll
    for (int j = 0; j < PA_EPT; j++) {
        if (ed[j] >= 0) {
            int b = ed[j] >> 8;
            int r = atomicAdd(&fill[b], 1);
            int loc = binbase[b] + r;
            spair[loc] = ((u64)(unsigned)ed[j] << 32) | (unsigned)es[j];
        }
    }
    __syncthreads();

    for (int i = tid; i < cnt; i += 256) {
        u64 p = spair[i];
        int b = (int)(p >> 40);                        // dst>>8 from packed pair
        int gi = gbase[b] + (i - binbase[b]);
        pairs[gi] = p;
        dstb[gi] = (u8)(p >> 32);                      // d & 255 (node id in bucket)
    }
}

// ---------------------------------------------------------------------------
// k_aggslim: one block (256 thr) per 16 nodes (3136 blocks, XCD-swizzled so
// a coarse bucket's 16 blocks share one XCD L2). Phase A: scan the bucket's
// dstb u8 stream as packed u32 (4 records/load), on match (1/16) load src
// from pairs + el[s], build 16x64-slot LDS lists with w inline. Phase B:
// 8-deep wave-per-node feat2 gather (32-bit voffset addressing) + inline
// denominator. Phase C: 16x64 MFMA output tile.
__global__ __launch_bounds__(256) void k_aggslim(const u64* __restrict__ pairs,
                                                 const u8* __restrict__ dstb,
                                                 const int* __restrict__ bcnt,
                                                 const float* __restrict__ el,
                                                 const float* __restrict__ er,
                                                 const unsigned* __restrict__ feat2,
                                                 const float* __restrict__ bias,
                                                 const u16* __restrict__ pWl,
                                                 float* __restrict__ out) {
    __shared__ int   cnt_l[AGN];
    __shared__ float erl[AGN];
    __shared__ int   ssrc[AGN * AGSLOT];               // 4 KB
    __shared__ float swgt[AGN * AGSLOT];               // 4 KB
    __shared__ unsigned sg[AGN * 68];                  // 4.35 KB

    int tid = threadIdx.x;
    int wave = tid >> 6, lane = tid & 63;
    // XCD-bijective swizzle: 3136 = 8 * 392; bucket's 16 blocks -> one XCD.
    int logical = (blockIdx.x & 7) * 392 + (blockIdx.x >> 3);
    int nb = logical * AGN;
    if (nb >= NNODES) return;
    int cb = logical >> 4;                             // coarse 256-node bucket
    int nblo = (logical & 15) * AGN;                   // nb & 255

    if (tid < AGN) {
        cnt_l[tid] = 0;
        erl[tid] = er[nb + tid];
    }
    __syncthreads();

    // ---- phase A: u8 scan + attention weight + LDS list build ----
    int cntb = bcnt[cb];
    const unsigned* db = (const unsigned*)(dstb + (size_t)cb * BCAP);
    const unsigned* sp = (const unsigned*)(pairs + (size_t)cb * BCAP); // [2*i] = src
    int nw = (cntb + 3) >> 2;
    for (int i = tid; i < nw; i += 256) {
        unsigned v = db[i];
        int base4 = i << 2;
#pragma unroll
        for (int j = 0; j < 4; j++) {
            int dl = (int)((v >> (8 * j)) & 255u) - nblo;
            if ((unsigned)dl < (unsigned)AGN && base4 + j < cntb) {
                int s = (int)sp[(base4 + j) * 2];
                float w = lrelu02_exp(el[s] + erl[dl]);
                int slot = atomicAdd(&cnt_l[dl], 1);
                if (slot < AGSLOT) {
                    ssrc[dl * AGSLOT + slot] = s;
                    swgt[dl * AGSLOT + slot] = w;
                }
            }
        }
    }
    __syncthreads();

    // ---- phase B: wave-per-node gather + normalize ----
    const char* fb = (const char*)feat2;
    unsigned co = (unsigned)(lane << 2);
    float bl = bias[lane * 2 + 0], bh = bias[lane * 2 + 1];
    for (int i = 0; i < 4; i++) {
        int dl = wave * 4 + i;
        int cnt = cnt_l[dl]; if (cnt > AGSLOT) cnt = AGSLOT;
        const int*   ep = ssrc + dl * AGSLOT;
        const float* wp = swgt + dl * AGSLOT;

        float p0 = 0.f, p1 = 0.f, q0 = 0.f, q1 = 0.f;
        float r0 = 0.f, r1 = 0.f, t0 = 0.f, t1 = 0.f;
        float u0 = 0.f, u1 = 0.f, x0 = 0.f, x1 = 0.f;
        float y0 = 0.f, y1 = 0.f, z0 = 0.f, z1 = 0.f;
        float dn = 0.f;
        int j = 0;
        for (; j + 8 <= cnt; j += 8) {
            int4 sa = *reinterpret_cast<const int4*>(ep + j);
            int4 sb = *reinterpret_cast<const int4*>(ep + j + 4);
            float4 wa = *reinterpret_cast<const float4*>(wp + j);
            float4 wb = *reinterpret_cast<const float4*>(wp + j + 4);
            unsigned v0 = *(const unsigned*)(fb + (((unsigned)sa.x << 8) + co));
            unsigned v1 = *(const unsigned*)(fb + (((unsigned)sa.y << 8) + co));
            unsigned v2 = *(const unsigned*)(fb + (((unsigned)sa.z << 8) + co));
            unsigned v3 = *(const unsigned*)(fb + (((unsigned)sa.w << 8) + co));
            unsigned v4 = *(const unsigned*)(fb + (((unsigned)sb.x << 8) + co));
            unsigned v5 = *(const unsigned*)(fb + (((unsigned)sb.y << 8) + co));
            unsigned v6 = *(const unsigned*)(fb + (((unsigned)sb.z << 8) + co));
            unsigned v7 = *(const unsigned*)(fb + (((unsigned)sb.w << 8) + co));
            p0 += wa.x * b2f_lo(v0); p1 += wa.x * b2f_hi(v0);
            q0 += wa.y * b2f_lo(v1); q1 += wa.y * b2f_hi(v1);
            r0 += wa.z * b2f_lo(v2); r1 += wa.z * b2f_hi(v2);
            t0 += wa.w * b2f_lo(v3); t1 += wa.w * b2f_hi(v3);
            u0 += wb.x * b2f_lo(v4); u1 += wb.x * b2f_hi(v4);
            x0 += wb.y * b2f_lo(v5); x1 += wb.y * b2f_hi(v5);
            y0 += wb.z * b2f_lo(v6); y1 += wb.z * b2f_hi(v6);
            z0 += wb.w * b2f_lo(v7); z1 += wb.w * b2f_hi(v7);
            dn += ((wa.x + wa.y) + (wa.z + wa.w)) + ((wb.x + wb.y) + (wb.z + wb.w));
        }
        if (j + 4 <= cnt) {
            int4 sa = *reinterpret_cast<const int4*>(ep + j);
            float4 wa = *reinterpret_cast<const float4*>(wp + j);
            unsigned v0 = *(const unsigned*)(fb + (((unsigned)sa.x << 8) + co));
            unsigned v1 = *(const unsigned*)(fb + (((unsigned)sa.y << 8) + co));
            unsigned v2 = *(const unsigned*)(fb + (((unsigned)sa.z << 8) + co));
            unsigned v3 = *(const unsigned*)(fb + (((unsigned)sa.w << 8) + co));
            p0 += wa.x * b2f_lo(v0); p1 += wa.x * b2f_hi(v0);
            q0 += wa.y * b2f_lo(v1); q1 += wa.y * b2f_hi(v1);
            r0 += wa.z * b2f_lo(v2); r1 += wa.z * b2f_hi(v2);
            t0 += wa.w * b2f_lo(v3); t1 += wa.w * b2f_hi(v3);
            dn += (wa.x + wa.y) + (wa.z + wa.w);
            j += 4;
        }
        for (; j < cnt; j++) {
            int s = ep[j];
            float w = wp[j];
            unsigned v = *(const unsigned*)(fb + (((unsigned)s << 8) + co));
            p0 += w * b2f_lo(v); p1 += w * b2f_hi(v);
            dn += w;
        }
        float a0 = ((p0 + q0) + (r0 + t0)) + ((u0 + x0) + (y0 + z0));
        float a1 = ((p1 + q1) + (r1 + t1)) + ((u1 + x1) + (y1 + z1));

        float inv = dn > 0.f ? 1.f / dn : 0.f;         // isolated node -> 0
        float g0 = a0 * inv + bl;
        float g1 = a1 * inv + bh;
        g0 = g0 > 0.f ? g0 : 0.01f * g0;               // leaky_relu(0.01)
        g1 = g1 > 0.f ? g1 : 0.01f * g1;
        sg[(wave * 4 + i) * 68 + lane] = (unsigned)f2b(g0) | ((unsigned)f2b(g1) << 16);
    }
    __syncthreads();

    // ---- phase C: 16x64 output GEMM ----
    int col = lane & 15, quad = lane >> 4;
    int nt = wave;
    f32x4 acc = {};
#pragma unroll
    for (int kt = 0; kt < 4; kt++) {
        bf16x8 a = *reinterpret_cast<const bf16x8*>(&sg[col * 68 + kt * 16 + quad * 4]);
        bf16x8 bf = *reinterpret_cast<const bf16x8*>(pWl + ((kt * 4 + nt) * 64 + lane) * 8);
        acc = __builtin_amdgcn_mfma_f32_16x16x32_bf16(a, bf, acc, 0, 0, 0);
    }
#pragma unroll
    for (int reg = 0; reg < 4; reg++)
        out[(size_t)(nb + quad * 4 + reg) * OUTF + nt * 16 + col] = acc[reg];
}

// ---------------------------------------------------------------------------
extern "C" void kernel_launch(void* const* d_in, const int* in_sizes, int n_in,
                              void* d_out, int out_size, void* d_ws, size_t ws_size,
                              hipStream_t stream) {
    const float* x      = (const float*)d_in[0];   // [50000,256] fp32
    const int*   src    = (const int*)d_in[1];     // [800000] int32
    const int*   dst    = (const int*)d_in[2];     // [800000] int32
    const float* Wg     = (const float*)d_in[3];   // [256,128] fp32
    const float* attn_l = (const float*)d_in[4];   // [128]
    const float* attn_r = (const float*)d_in[5];   // [128]
    const float* bias   = (const float*)d_in[6];   // [128]
    const float* Wl     = (const float*)d_in[7];   // [64,128] fp32
    float* out          = (float*)d_out;           // [50000,64] fp32

    char* ws = (char*)d_ws;
    size_t off = 0;
    auto alloc = [&](size_t b) { size_t r = off; off += (b + 255) & ~(size_t)255; return r; };
    size_t pwgOff  = alloc((size_t)8 * 8 * 64 * 8 * 2);     // 64 KB
    size_t pwlOff  = alloc((size_t)4 * 4 * 64 * 8 * 2);     // 16 KB
    size_t featOff = alloc((size_t)NNODES * HID * 2);       // 12.8 MB bf16 feat
    size_t elOff   = alloc((size_t)NNODES * 4);
    size_t erOff   = alloc((size_t)NNODES * 4);
    size_t pairOff = alloc((size_t)NBKT * BCAP * 8);        // 8.0 MB bucket regions
    size_t dstbOff = alloc((size_t)NBKT * BCAP);            // 1.0 MB u8 stream
    size_t bcntOff = alloc((size_t)NBKT * 4);

    u16*      pWg   = (u16*)(ws + pwgOff);
    u16*      pWl   = (u16*)(ws + pwlOff);
    unsigned* feat2 = (unsigned*)(ws + featOff);
    float*    el    = (float*)(ws + elOff);
    float*    er    = (float*)(ws + erOff);
    u64*      pairs = (u64*)(ws + pairOff);
    u8*       dstb  = (u8*)(ws + dstbOff);
    int*      bcnt  = (int*)(ws + bcntOff);

    pack0<<<21, 256, 0, stream>>>(Wg, Wl, pWg, pWl, bcnt);
    k_mega<<<GB + PA_NB, 256, 0, stream>>>(x, pWg, attn_l, attn_r, feat2, el, er,
                                           src, dst, bcnt, pairs, dstb);
    k_aggslim<<<AGB, 256, 0, stream>>>(pairs, dstb, bcnt, el, er, feat2, bias,
                                       pWl, out);
}

// Round 10
// 168.232 us; speedup vs baseline: 1.0521x; 1.0017x over previous
//
#include <hip/hip_runtime.h>
#include <hip/hip_bf16.h>

// GAT layer on MI355X. Round 25: REGISTER BUDGET is the one variable.
// Rounds 7/9 profiles show k_mega/k_aggslim at 36-56 VGPR: the allocator
// ROLLED the 16 hoisted GEMM loads (need 64 VGPR) and k_aggslim's 8-deep
// gather batch back into ~2-reg loops -> per-wave MLP ~2 -> every kernel
// latency-bound at ~1-2 TB/s regardless of structure (the recurring 45-50 us
// band). Fix: generous VGPR caps via launch_bounds min-waves:
//   k_mega    (256,2) -> cap 256 VGPR (16 x-loads + 8 av + 32 acc live)
//   k_aggslim (256,4) -> cap 128 VGPR (8 loads + 8 weights + 16 acc live)
// Everything else byte-identical to round 6 (best wall 165.1; round-9's
// dstb/u8 scan reverted: FETCH proved gather-side, scan bytes irrelevant).
// 3 dispatches.

#define NNODES 50000
#define NEDGES 800000
#define IN_F   256
#define HID    128
#define OUTF   64

#define PA_EPT   8
#define PA_EDGES (256 * PA_EPT)                          // 2048 edges/block
#define PA_NB    ((NEDGES + PA_EDGES - 1) / PA_EDGES)    // 391 blocks
#define NBKT     ((NNODES + 255) / 256)                  // 196 buckets (dst>>8)
#define BCAP     5120                                    // bucket capacity (lam=4082)
#define NSTRIP   (NNODES / 16)                           // 3125 strips
#define GB       ((NSTRIP + 3) / 4)                      // 782 gemm blocks

#define AGN      16                                      // nodes per agg block
#define AGSLOT   64                                      // per-node LDS slot cap (max deg ~45)
#define AGB      3136                                    // 8 * 392 agg blocks (>= 3125)

typedef unsigned short u16;
typedef unsigned long long u64;
typedef __bf16 bf16x8 __attribute__((ext_vector_type(8)));
typedef float  f32x4  __attribute__((ext_vector_type(4)));

__device__ __forceinline__ u16 f2b(float f) {
    union { float f; unsigned u; } v; v.f = f;
    unsigned u = v.u;
    return (u16)((u + 0x7fffu + ((u >> 16) & 1u)) >> 16);  // RNE fp32->bf16
}
__device__ __forceinline__ float b2f_lo(unsigned v) {
    union { unsigned u; float f; } c; c.u = (v & 0xffffu) << 16; return c.f;
}
__device__ __forceinline__ float b2f_hi(unsigned v) {
    union { unsigned u; float f; } c; c.u = v & 0xffff0000u; return c.f;
}
__device__ __forceinline__ float lrelu02_exp(float t) {
    t = t > 0.f ? t : 0.2f * t;                        // leaky_relu(0.2)
    return __expf(t);
}

// ---------------------------------------------------------------------------
// pack0: blocks 0..15 pack W_gat, 16..19 pack W_lin, 20 zeroes bcnt.
__global__ __launch_bounds__(256) void pack0(const float* __restrict__ Wg,
                                             const float* __restrict__ Wl,
                                             u16* __restrict__ pWg,
                                             u16* __restrict__ pWl,
                                             int* __restrict__ bcnt) {
    int blk = blockIdx.x, tid = threadIdx.x;
    if (blk < 16) {
        int t = blk * 256 + tid;
        int lane = t & 63, tile = t >> 6;
        int nt = tile & 7, kt = tile >> 3;
        int col = lane & 15, quad = lane >> 4;
        int krow = kt * 32 + quad * 8;
        int ncol = nt * 16 + col;
#pragma unroll
        for (int j = 0; j < 8; j++) pWg[t * 8 + j] = f2b(Wg[(krow + j) * HID + ncol]);
    } else if (blk < 20) {
        int t = (blk - 16) * 256 + tid;
        int lane = t & 63, tile = t >> 6;
        int nt = tile & 3, kt = tile >> 2;
        int col = lane & 15, quad = lane >> 4;
        int o  = nt * 16 + col;
        int k0 = kt * 32 + quad * 8;
#pragma unroll
        for (int j = 0; j < 8; j++) pWl[t * 8 + j] = f2b(Wl[o * HID + k0 + j]);
    } else {
        if (tid < NBKT) bcnt[tid] = 0;
    }
}

// ---------------------------------------------------------------------------
// k_mega: blocks [0,GB) = feat GEMM (1 strip/wave, 16 hoisted x-loads,
// fused el/er epilogue); blocks [GB, GB+PA_NB) = edge partition into 196
// bucket regions. launch_bounds(256,2): VGPR cap 256 so the 16 loads stay
// physically hoisted (round-9 profile: 36 VGPR = loads rolled, MLP ~2).
__global__ __launch_bounds__(256, 2) void k_mega(
        const float* __restrict__ x, const u16* __restrict__ pWg,
        const float* __restrict__ al_, const float* __restrict__ ar_,
        unsigned* __restrict__ feat2, float* __restrict__ el, float* __restrict__ er,
        const int* __restrict__ src, const int* __restrict__ dst,
        int* __restrict__ bcnt, u64* __restrict__ pairs) {
    __shared__ u64 smemU[21504 / 8];
    char* smem = (char*)smemU;
    int blk = blockIdx.x, tid = threadIdx.x;

    if (blk < GB) {
        // ---- feat GEMM path (no LDS use) ----
        int wave = tid >> 6, lane = tid & 63;
        int strip = blk * 4 + wave;
        if (strip >= NSTRIP) return;
        int m0 = strip * 16;
        int col = lane & 15, quad = lane >> 4;

        // hoist ALL x loads for this strip: 16 independent 16B loads/lane
        f32x4 xa[16];
        const float* xr = x + (size_t)(m0 + col) * IN_F + quad * 8;
#pragma unroll
        for (int kt = 0; kt < 8; kt++) {
            xa[2 * kt]     = *reinterpret_cast<const f32x4*>(xr + kt * 32);
            xa[2 * kt + 1] = *reinterpret_cast<const f32x4*>(xr + kt * 32 + 4);
        }
        bf16x8 av[8];
#pragma unroll
        for (int kt = 0; kt < 8; kt++)
#pragma unroll
            for (int j = 0; j < 4; j++) {
                av[kt][j]     = (__bf16)xa[2 * kt][j];
                av[kt][4 + j] = (__bf16)xa[2 * kt + 1][j];
            }

        f32x4 acc[8] = {};
#pragma unroll
        for (int kt = 0; kt < 8; kt++)
#pragma unroll
            for (int nt = 0; nt < 8; nt++) {
                bf16x8 b = *reinterpret_cast<const bf16x8*>(pWg + ((kt * 8 + nt) * 64 + lane) * 8);
                acc[nt] = __builtin_amdgcn_mfma_f32_16x16x32_bf16(av[kt], b, acc[nt], 0, 0, 0);
            }

        // epilogue: el/er dot products + bf16 feat store
        float pl[4] = {0, 0, 0, 0}, pr[4] = {0, 0, 0, 0};
#pragma unroll
        for (int nt = 0; nt < 8; nt++) {
            float alv = al_[nt * 16 + col], arv = ar_[nt * 16 + col];
#pragma unroll
            for (int reg = 0; reg < 4; reg++) {
                pl[reg] += acc[nt][reg] * alv;
                pr[reg] += acc[nt][reg] * arv;
            }
        }
#pragma unroll
        for (int m = 1; m < 16; m <<= 1)
#pragma unroll
            for (int reg = 0; reg < 4; reg++) {
                pl[reg] += __shfl_xor(pl[reg], m, 64);
                pr[reg] += __shfl_xor(pr[reg], m, 64);
            }
        if (col == 0) {
#pragma unroll
            for (int reg = 0; reg < 4; reg++) {
                el[m0 + quad * 4 + reg] = pl[reg];
                er[m0 + quad * 4 + reg] = pr[reg];
            }
        }
#pragma unroll
        for (int nt = 0; nt < 8; nt++)
#pragma unroll
            for (int reg = 0; reg < 4; reg++) {
                u16* fp = (u16*)feat2;
                fp[(size_t)(m0 + quad * 4 + reg) * HID + nt * 16 + col] = f2b(acc[nt][reg]);
            }
        return;
    }

    // ---- edge partition path ----
    int* hist    = (int*)smem;                         // 256 ints (196 used)
    int* binbase = hist + 256;
    int* gbase   = binbase + 256;
    int* fill    = gbase + 256;
    int* stmp    = fill + 256;                         // 256 ints -> 5120 B
    u64* spair   = (u64*)(smem + 5120);                // 2048 * 8 = 16384 B

    int e0 = (blk - GB) * PA_EDGES;
    int cnt = NEDGES - e0; if (cnt > PA_EDGES) cnt = PA_EDGES;

    hist[tid] = 0; fill[tid] = 0;
    __syncthreads();

    int es[PA_EPT], ed[PA_EPT];
#pragma unroll
    for (int j = 0; j < PA_EPT; j++) {
        int idx = e0 + j * 256 + tid;
        if (idx < NEDGES) {
            es[j] = src[idx];
            ed[j] = dst[idx];
            atomicAdd(&hist[ed[j] >> 8], 1);
        } else ed[j] = -1;
    }
    __syncthreads();

    stmp[tid] = (tid < NBKT) ? hist[tid] : 0;
    __syncthreads();
#pragma unroll
    for (int ofs = 1; ofs < 256; ofs <<= 1) {
        int u = (tid >= ofs) ? stmp[tid - ofs] : 0;
        __syncthreads();
        stmp[tid] += u;
        __syncthreads();
    }
    if (tid < NBKT) {
        binbase[tid] = stmp[tid] - hist[tid];
        if (hist[tid] > 0)
            gbase[tid] = tid * BCAP + atomicAdd(&bcnt[tid], hist[tid]);
    }
    __syncthreads();

#pragma unroll
    for (int j = 0; j < PA_EPT; j++) {
        if (ed[j] >= 0) {
            int b = ed[j] >> 8;
            int r = atomicAdd(&fill[b], 1);
            int loc = binbase[b] + r;
            spair[loc] = ((u64)(unsigned)ed[j] << 32) | (unsigned)es[j];
        }
    }
    __syncthreads();

    for (int i = tid; i < cnt; i += 256) {
        u64 p = spair[i];
        int b = (int)(p >> 40);                        // dst>>8 from packed pair
        pairs[gbase[b] + (i - binbase[b])] = p;
    }
}

// ---------------------------------------------------------------------------
// k_aggslim: one block (256 thr) per 16 nodes (3136 blocks, XCD-swizzled so
// a coarse bucket's 16 blocks share one XCD L2). launch_bounds(256,4):
// VGPR cap 128 so the 8-deep gather batch stays physically in flight
// (round-9 profile: 36 VGPR = batch serialized).
__global__ __launch_bounds__(256, 4) void k_aggslim(const u64* __restrict__ pairs,
                                                 const int* __restrict__ bcnt,
                                                 const float* __restrict__ el,
                                                 const float* __restrict__ er,
                                                 const unsigned* __restrict__ feat2,
                                                 const float* __restrict__ bias,
                                                 const u16* __restrict__ pWl,
                                                 float* __restrict__ out) {
    __shared__ int   cnt_l[AGN];
    __shared__ float erl[AGN];
    __shared__ int   ssrc[AGN * AGSLOT];               // 4 KB
    __shared__ float swgt[AGN * AGSLOT];               // 4 KB
    __shared__ unsigned sg[AGN * 68];                  // 4.35 KB

    int tid = threadIdx.x;
    int wave = tid >> 6, lane = tid & 63;
    // XCD-bijective swizzle: 3136 = 8 * 392; bucket's 16 blocks -> one XCD.
    int logical = (blockIdx.x & 7) * 392 + (blockIdx.x >> 3);
    int nb = logical * AGN;
    if (nb >= NNODES) return;
    int cb = logical >> 4;                             // coarse 256-node bucket

    if (tid < AGN) {
        cnt_l[tid] = 0;
        erl[tid] = er[nb + tid];
    }
    __syncthreads();

    // ---- phase A: filter + attention weight + LDS list build ----
    int cntb = bcnt[cb];
    const u64* reg = pairs + (size_t)cb * BCAP;
    for (int i = tid; i < cntb; i += 256) {
        u64 p = reg[i];
        int d = (int)(unsigned)(p >> 32);
        unsigned dl = (unsigned)(d - nb);
        if (dl < (unsigned)AGN) {
            int s = (int)(unsigned)(p & 0xffffffffu);
            float w = lrelu02_exp(el[s] + erl[dl]);
            int slot = atomicAdd(&cnt_l[dl], 1);
            if (slot < AGSLOT) {
                ssrc[dl * AGSLOT + slot] = s;
                swgt[dl * AGSLOT + slot] = w;
            }
        }
    }
    __syncthreads();

    // ---- phase B: wave-per-node gather + normalize ----
    float bl = bias[lane * 2 + 0], bh = bias[lane * 2 + 1];
    for (int i = 0; i < 4; i++) {
        int dl = wave * 4 + i;
        int cnt = cnt_l[dl]; if (cnt > AGSLOT) cnt = AGSLOT;
        const int*   ep = ssrc + dl * AGSLOT;
        const float* wp = swgt + dl * AGSLOT;

        float p0 = 0.f, p1 = 0.f, q0 = 0.f, q1 = 0.f;
        float r0 = 0.f, r1 = 0.f, t0 = 0.f, t1 = 0.f;
        float u0 = 0.f, u1 = 0.f, x0 = 0.f, x1 = 0.f;
        float y0 = 0.f, y1 = 0.f, z0 = 0.f, z1 = 0.f;
        float dn = 0.f;
        int j = 0;
        for (; j + 8 <= cnt; j += 8) {
            int4 sa = *reinterpret_cast<const int4*>(ep + j);
            int4 sb = *reinterpret_cast<const int4*>(ep + j + 4);
            float4 wa = *reinterpret_cast<const float4*>(wp + j);
            float4 wb = *reinterpret_cast<const float4*>(wp + j + 4);
            unsigned v0 = feat2[(size_t)sa.x * 64 + lane];
            unsigned v1 = feat2[(size_t)sa.y * 64 + lane];
            unsigned v2 = feat2[(size_t)sa.z * 64 + lane];
            unsigned v3 = feat2[(size_t)sa.w * 64 + lane];
            unsigned v4 = feat2[(size_t)sb.x * 64 + lane];
            unsigned v5 = feat2[(size_t)sb.y * 64 + lane];
            unsigned v6 = feat2[(size_t)sb.z * 64 + lane];
            unsigned v7 = feat2[(size_t)sb.w * 64 + lane];
            p0 += wa.x * b2f_lo(v0); p1 += wa.x * b2f_hi(v0);
            q0 += wa.y * b2f_lo(v1); q1 += wa.y * b2f_hi(v1);
            r0 += wa.z * b2f_lo(v2); r1 += wa.z * b2f_hi(v2);
            t0 += wa.w * b2f_lo(v3); t1 += wa.w * b2f_hi(v3);
            u0 += wb.x * b2f_lo(v4); u1 += wb.x * b2f_hi(v4);
            x0 += wb.y * b2f_lo(v5); x1 += wb.y * b2f_hi(v5);
            y0 += wb.z * b2f_lo(v6); y1 += wb.z * b2f_hi(v6);
            z0 += wb.w * b2f_lo(v7); z1 += wb.w * b2f_hi(v7);
            dn += ((wa.x + wa.y) + (wa.z + wa.w)) + ((wb.x + wb.y) + (wb.z + wb.w));
        }
        if (j + 4 <= cnt) {
            int4 sa = *reinterpret_cast<const int4*>(ep + j);
            float4 wa = *reinterpret_cast<const float4*>(wp + j);
            unsigned v0 = feat2[(size_t)sa.x * 64 + lane];
            unsigned v1 = feat2[(size_t)sa.y * 64 + lane];
            unsigned v2 = feat2[(size_t)sa.z * 64 + lane];
            unsigned v3 = feat2[(size_t)sa.w * 64 + lane];
            p0 += wa.x * b2f_lo(v0); p1 += wa.x * b2f_hi(v0);
            q0 += wa.y * b2f_lo(v1); q1 += wa.y * b2f_hi(v1);
            r0 += wa.z * b2f_lo(v2); r1 += wa.z * b2f_hi(v2);
            t0 += wa.w * b2f_lo(v3); t1 += wa.w * b2f_hi(v3);
            dn += (wa.x + wa.y) + (wa.z + wa.w);
            j += 4;
        }
        for (; j < cnt; j++) {
            int s = ep[j];
            float w = wp[j];
            unsigned v = feat2[(size_t)s * 64 + lane];
            p0 += w * b2f_lo(v); p1 += w * b2f_hi(v);
            dn += w;
        }
        float a0 = ((p0 + q0) + (r0 + t0)) + ((u0 + x0) + (y0 + z0));
        float a1 = ((p1 + q1) + (r1 + t1)) + ((u1 + x1) + (y1 + z1));

        float inv = dn > 0.f ? 1.f / dn : 0.f;         // isolated node -> 0
        float g0 = a0 * inv + bl;
        float g1 = a1 * inv + bh;
        g0 = g0 > 0.f ? g0 : 0.01f * g0;               // leaky_relu(0.01)
        g1 = g1 > 0.f ? g1 : 0.01f * g1;
        sg[(wave * 4 + i) * 68 + lane] = (unsigned)f2b(g0) | ((unsigned)f2b(g1) << 16);
    }
    __syncthreads();

    // ---- phase C: 16x64 output GEMM ----
    int col = lane & 15, quad = lane >> 4;
    int nt = wave;
    f32x4 acc = {};
#pragma unroll
    for (int kt = 0; kt < 4; kt++) {
        bf16x8 a = *reinterpret_cast<const bf16x8*>(&sg[col * 68 + kt * 16 + quad * 4]);
        bf16x8 bf = *reinterpret_cast<const bf16x8*>(pWl + ((kt * 4 + nt) * 64 + lane) * 8);
        acc = __builtin_amdgcn_mfma_f32_16x16x32_bf16(a, bf, acc, 0, 0, 0);
    }
#pragma unroll
    for (int reg = 0; reg < 4; reg++)
        out[(size_t)(nb + quad * 4 + reg) * OUTF + nt * 16 + col] = acc[reg];
}

// ---------------------------------------------------------------------------
extern "C" void kernel_launch(void* const* d_in, const int* in_sizes, int n_in,
                              void* d_out, int out_size, void* d_ws, size_t ws_size,
                              hipStream_t stream) {
    const float* x      = (const float*)d_in[0];   // [50000,256] fp32
    const int*   src    = (const int*)d_in[1];     // [800000] int32
    const int*   dst    = (const int*)d_in[2];     // [800000] int32
    const float* Wg     = (const float*)d_in[3];   // [256,128] fp32
    const float* attn_l = (const float*)d_in[4];   // [128]
    const float* attn_r = (const float*)d_in[5];   // [128]
    const float* bias   = (const float*)d_in[6];   // [128]
    const float* Wl     = (const float*)d_in[7];   // [64,128] fp32
    float* out          = (float*)d_out;           // [50000,64] fp32

    char* ws = (char*)d_ws;
    size_t off = 0;
    auto alloc = [&](size_t b) { size_t r = off; off += (b + 255) & ~(size_t)255; return r; };
    size_t pwgOff  = alloc((size_t)8 * 8 * 64 * 8 * 2);     // 64 KB
    size_t pwlOff  = alloc((size_t)4 * 4 * 64 * 8 * 2);     // 16 KB
    size_t featOff = alloc((size_t)NNODES * HID * 2);       // 12.8 MB bf16 feat
    size_t elOff   = alloc((size_t)NNODES * 4);
    size_t erOff   = alloc((size_t)NNODES * 4);
    size_t pairOff = alloc((size_t)NBKT * BCAP * 8);        // 8.0 MB bucket regions
    size_t bcntOff = alloc((size_t)NBKT * 4);

    u16*      pWg   = (u16*)(ws + pwgOff);
    u16*      pWl   = (u16*)(ws + pwlOff);
    unsigned* feat2 = (unsigned*)(ws + featOff);
    float*    el    = (float*)(ws + elOff);
    float*    er    = (float*)(ws + erOff);
    u64*      pairs = (u64*)(ws + pairOff);
    int*      bcnt  = (int*)(ws + bcntOff);

    pack0<<<21, 256, 0, stream>>>(Wg, Wl, pWg, pWl, bcnt);
    k_mega<<<GB + PA_NB, 256, 0, stream>>>(x, pWg, attn_l, attn_r, feat2, el, er,
                                           src, dst, bcnt, pairs);
    k_aggslim<<<AGB, 256, 0, stream>>>(pairs, bcnt, el, er, feat2, bias,
                                       pWl, out);
}

// Round 11
// 167.596 us; speedup vs baseline: 1.0561x; 1.0038x over previous
//
#include <hip/hip_runtime.h>
#include <hip/hip_bf16.h>

// GAT layer on MI355X. Round 26: restructure k_aggslim phase B at SOURCE
// level. Round-10 falsified the register-budget theory: launch_bounds caps
// but never encourages liveness (VGPR stayed 32, dur 48). So make each
// instruction do more work instead:
//  - 16 lanes/edge, dwordx4 (16B) loads: 1 VMEM inst = 4 edges (was 1),
//    addressing VALU /4, branch-free slot loop via w=0 sentinels.
//  - (w,s) packed u64 in LDS: 1 ds_read_b64 per edge-pair fetch.
//  - denominator via ds_add_f32 in phase A (kills the dn chain).
//  - 2 shfl_xor folds combine the 4 edge groups; phase C unchanged.
// k_mega / pack0 / partition byte-identical to round 6 (best wall 165.1).
// 3 dispatches.

#define NNODES 50000
#define NEDGES 800000
#define IN_F   256
#define HID    128
#define OUTF   64

#define PA_EPT   8
#define PA_EDGES (256 * PA_EPT)                          // 2048 edges/block
#define PA_NB    ((NEDGES + PA_EDGES - 1) / PA_EDGES)    // 391 blocks
#define NBKT     ((NNODES + 255) / 256)                  // 196 buckets (dst>>8)
#define BCAP     5120                                    // bucket capacity (lam=4082)
#define NSTRIP   (NNODES / 16)                           // 3125 strips
#define GB       ((NSTRIP + 3) / 4)                      // 782 gemm blocks

#define AGN      16                                      // nodes per agg block
#define AGSLOT   64                                      // per-node LDS slot cap (max deg ~45)
#define AGB      3136                                    // 8 * 392 agg blocks (>= 3125)

typedef unsigned short u16;
typedef unsigned long long u64;
typedef __bf16 bf16x8 __attribute__((ext_vector_type(8)));
typedef float  f32x4  __attribute__((ext_vector_type(4)));

__device__ __forceinline__ u16 f2b(float f) {
    union { float f; unsigned u; } v; v.f = f;
    unsigned u = v.u;
    return (u16)((u + 0x7fffu + ((u >> 16) & 1u)) >> 16);  // RNE fp32->bf16
}
__device__ __forceinline__ float b2f_lo(unsigned v) {
    union { unsigned u; float f; } c; c.u = (v & 0xffffu) << 16; return c.f;
}
__device__ __forceinline__ float b2f_hi(unsigned v) {
    union { unsigned u; float f; } c; c.u = v & 0xffff0000u; return c.f;
}
__device__ __forceinline__ float lrelu02_exp(float t) {
    t = t > 0.f ? t : 0.2f * t;                        // leaky_relu(0.2)
    return __expf(t);
}

// ---------------------------------------------------------------------------
// pack0: blocks 0..15 pack W_gat, 16..19 pack W_lin, 20 zeroes bcnt.
__global__ __launch_bounds__(256) void pack0(const float* __restrict__ Wg,
                                             const float* __restrict__ Wl,
                                             u16* __restrict__ pWg,
                                             u16* __restrict__ pWl,
                                             int* __restrict__ bcnt) {
    int blk = blockIdx.x, tid = threadIdx.x;
    if (blk < 16) {
        int t = blk * 256 + tid;
        int lane = t & 63, tile = t >> 6;
        int nt = tile & 7, kt = tile >> 3;
        int col = lane & 15, quad = lane >> 4;
        int krow = kt * 32 + quad * 8;
        int ncol = nt * 16 + col;
#pragma unroll
        for (int j = 0; j < 8; j++) pWg[t * 8 + j] = f2b(Wg[(krow + j) * HID + ncol]);
    } else if (blk < 20) {
        int t = (blk - 16) * 256 + tid;
        int lane = t & 63, tile = t >> 6;
        int nt = tile & 3, kt = tile >> 2;
        int col = lane & 15, quad = lane >> 4;
        int o  = nt * 16 + col;
        int k0 = kt * 32 + quad * 8;
#pragma unroll
        for (int j = 0; j < 8; j++) pWl[t * 8 + j] = f2b(Wl[o * HID + k0 + j]);
    } else {
        if (tid < NBKT) bcnt[tid] = 0;
    }
}

// ---------------------------------------------------------------------------
// k_mega: blocks [0,GB) = feat GEMM (1 strip/wave, 16 hoisted x-loads,
// fused el/er epilogue); blocks [GB, GB+PA_NB) = edge partition into 196
// bucket regions. Byte-identical to round 6.
__global__ __launch_bounds__(256) void k_mega(
        const float* __restrict__ x, const u16* __restrict__ pWg,
        const float* __restrict__ al_, const float* __restrict__ ar_,
        unsigned* __restrict__ feat2, float* __restrict__ el, float* __restrict__ er,
        const int* __restrict__ src, const int* __restrict__ dst,
        int* __restrict__ bcnt, u64* __restrict__ pairs) {
    __shared__ u64 smemU[21504 / 8];
    char* smem = (char*)smemU;
    int blk = blockIdx.x, tid = threadIdx.x;

    if (blk < GB) {
        // ---- feat GEMM path (no LDS use) ----
        int wave = tid >> 6, lane = tid & 63;
        int strip = blk * 4 + wave;
        if (strip >= NSTRIP) return;
        int m0 = strip * 16;
        int col = lane & 15, quad = lane >> 4;

        // hoist ALL x loads for this strip: 16 independent 16B loads/lane
        f32x4 xa[16];
        const float* xr = x + (size_t)(m0 + col) * IN_F + quad * 8;
#pragma unroll
        for (int kt = 0; kt < 8; kt++) {
            xa[2 * kt]     = *reinterpret_cast<const f32x4*>(xr + kt * 32);
            xa[2 * kt + 1] = *reinterpret_cast<const f32x4*>(xr + kt * 32 + 4);
        }
        bf16x8 av[8];
#pragma unroll
        for (int kt = 0; kt < 8; kt++)
#pragma unroll
            for (int j = 0; j < 4; j++) {
                av[kt][j]     = (__bf16)xa[2 * kt][j];
                av[kt][4 + j] = (__bf16)xa[2 * kt + 1][j];
            }

        f32x4 acc[8] = {};
#pragma unroll
        for (int kt = 0; kt < 8; kt++)
#pragma unroll
            for (int nt = 0; nt < 8; nt++) {
                bf16x8 b = *reinterpret_cast<const bf16x8*>(pWg + ((kt * 8 + nt) * 64 + lane) * 8);
                acc[nt] = __builtin_amdgcn_mfma_f32_16x16x32_bf16(av[kt], b, acc[nt], 0, 0, 0);
            }

        // epilogue: el/er dot products + bf16 feat store
        float pl[4] = {0, 0, 0, 0}, pr[4] = {0, 0, 0, 0};
#pragma unroll
        for (int nt = 0; nt < 8; nt++) {
            float alv = al_[nt * 16 + col], arv = ar_[nt * 16 + col];
#pragma unroll
            for (int reg = 0; reg < 4; reg++) {
                pl[reg] += acc[nt][reg] * alv;
                pr[reg] += acc[nt][reg] * arv;
            }
        }
#pragma unroll
        for (int m = 1; m < 16; m <<= 1)
#pragma unroll
            for (int reg = 0; reg < 4; reg++) {
                pl[reg] += __shfl_xor(pl[reg], m, 64);
                pr[reg] += __shfl_xor(pr[reg], m, 64);
            }
        if (col == 0) {
#pragma unroll
            for (int reg = 0; reg < 4; reg++) {
                el[m0 + quad * 4 + reg] = pl[reg];
                er[m0 + quad * 4 + reg] = pr[reg];
            }
        }
#pragma unroll
        for (int nt = 0; nt < 8; nt++)
#pragma unroll
            for (int reg = 0; reg < 4; reg++) {
                u16* fp = (u16*)feat2;
                fp[(size_t)(m0 + quad * 4 + reg) * HID + nt * 16 + col] = f2b(acc[nt][reg]);
            }
        return;
    }

    // ---- edge partition path ----
    int* hist    = (int*)smem;                         // 256 ints (196 used)
    int* binbase = hist + 256;
    int* gbase   = binbase + 256;
    int* fill    = gbase + 256;
    int* stmp    = fill + 256;                         // 256 ints -> 5120 B
    u64* spair   = (u64*)(smem + 5120);                // 2048 * 8 = 16384 B

    int e0 = (blk - GB) * PA_EDGES;
    int cnt = NEDGES - e0; if (cnt > PA_EDGES) cnt = PA_EDGES;

    hist[tid] = 0; fill[tid] = 0;
    __syncthreads();

    int es[PA_EPT], ed[PA_EPT];
#pragma unroll
    for (int j = 0; j < PA_EPT; j++) {
        int idx = e0 + j * 256 + tid;
        if (idx < NEDGES) {
            es[j] = src[idx];
            ed[j] = dst[idx];
            atomicAdd(&hist[ed[j] >> 8], 1);
        } else ed[j] = -1;
    }
    __syncthreads();

    stmp[tid] = (tid < NBKT) ? hist[tid] : 0;
    __syncthreads();
#pragma unroll
    for (int ofs = 1; ofs < 256; ofs <<= 1) {
        int u = (tid >= ofs) ? stmp[tid - ofs] : 0;
        __syncthreads();
        stmp[tid] += u;
        __syncthreads();
    }
    if (tid < NBKT) {
        binbase[tid] = stmp[tid] - hist[tid];
        if (hist[tid] > 0)
            gbase[tid] = tid * BCAP + atomicAdd(&bcnt[tid], hist[tid]);
    }
    __syncthreads();

#pragma unroll
    for (int j = 0; j < PA_EPT; j++) {
        if (ed[j] >= 0) {
            int b = ed[j] >> 8;
            int r = atomicAdd(&fill[b], 1);
            int loc = binbase[b] + r;
            spair[loc] = ((u64)(unsigned)ed[j] << 32) | (unsigned)es[j];
        }
    }
    __syncthreads();

    for (int i = tid; i < cnt; i += 256) {
        u64 p = spair[i];
        int b = (int)(p >> 40);                        // dst>>8 from packed pair
        pairs[gbase[b] + (i - binbase[b])] = p;
    }
}

// ---------------------------------------------------------------------------
// k_aggslim: one block (256 thr) per 16 nodes (3136 blocks, XCD-swizzled).
// Phase A: scan coarse bucket window, on match store packed (w,s) u64 into
// 16x64-slot LDS + ds_add_f32 denominator. Phase B: 16 lanes/edge dwordx4
// gather (1 VMEM = 4 edges), branch-free via w=0 sentinel slots, 2 shfl_xor
// folds. Phase C: 16x64 MFMA output tile (unchanged).
__global__ __launch_bounds__(256) void k_aggslim(const u64* __restrict__ pairs,
                                                 const int* __restrict__ bcnt,
                                                 const float* __restrict__ el,
                                                 const float* __restrict__ er,
                                                 const unsigned* __restrict__ feat2,
                                                 const float* __restrict__ bias,
                                                 const u16* __restrict__ pWl,
                                                 float* __restrict__ out) {
    __shared__ int   cnt_l[AGN];
    __shared__ float dls[AGN];
    __shared__ float erl[AGN];
    __shared__ u64   sws[AGN * AGSLOT];                // 8 KB packed (w,s)
    __shared__ unsigned sg[AGN * 68];                  // 4.35 KB

    int tid = threadIdx.x;
    int wave = tid >> 6, lane = tid & 63;
    // XCD-bijective swizzle: 3136 = 8 * 392; bucket's 16 blocks -> one XCD.
    int logical = (blockIdx.x & 7) * 392 + (blockIdx.x >> 3);
    int nb = logical * AGN;
    if (nb >= NNODES) return;
    int cb = logical >> 4;                             // coarse 256-node bucket

    if (tid < AGN) {
        cnt_l[tid] = 0;
        dls[tid] = 0.f;
        erl[tid] = er[nb + tid];
    }
    // zero-init slot array (w=0 sentinels make phase B branch-free)
    for (int i = tid; i < AGN * AGSLOT; i += 256) sws[i] = 0ull;
    __syncthreads();

    // ---- phase A: filter + attention weight + packed LDS store + denom ----
    int cntb = bcnt[cb];
    const u64* reg = pairs + (size_t)cb * BCAP;
    for (int i = tid; i < cntb; i += 256) {
        u64 p = reg[i];
        int d = (int)(unsigned)(p >> 32);
        unsigned dl = (unsigned)(d - nb);
        if (dl < (unsigned)AGN) {
            int s = (int)(unsigned)(p & 0xffffffffu);
            float w = lrelu02_exp(el[s] + erl[dl]);
            atomicAdd(&dls[dl], w);
            int slot = atomicAdd(&cnt_l[dl], 1);
            if (slot < AGSLOT) {
                union { float f; unsigned u; } wu; wu.f = w;
                sws[dl * AGSLOT + slot] = ((u64)wu.u << 32) | (unsigned)s;
            }
        }
    }
    __syncthreads();

    // ---- phase B: 4-edge-parallel gather (16 lanes/edge, dwordx4) ----
    int fl = lane & 15;                                // 16B feature chunk id
    int eg = lane >> 4;                                // edge group 0..3
    f32x4 bA = *reinterpret_cast<const f32x4*>(bias + fl * 8);
    f32x4 bB = *reinterpret_cast<const f32x4*>(bias + fl * 8 + 4);

    for (int i = 0; i < 4; i++) {
        int dl = wave * 4 + i;
        int cnt = cnt_l[dl]; if (cnt > AGSLOT) cnt = AGSLOT;
        int ng = (cnt + 7) >> 3;                       // 8-edge groups
        const u64* swp = sws + dl * AGSLOT + eg;

        float a0 = 0.f, a1 = 0.f, a2 = 0.f, a3 = 0.f;
        float a4 = 0.f, a5 = 0.f, a6 = 0.f, a7 = 0.f;
        for (int j = 0; j < ng; j++) {
            u64 ws0 = swp[j * 8];
            u64 ws1 = swp[j * 8 + 4];
            int s0 = (int)(unsigned)(ws0 & 0xffffffffu);
            int s1 = (int)(unsigned)(ws1 & 0xffffffffu);
            union { unsigned u; float f; } w0c, w1c;
            w0c.u = (unsigned)(ws0 >> 32);
            w1c.u = (unsigned)(ws1 >> 32);
            float w0 = w0c.f, w1 = w1c.f;
            uint4 v0 = *reinterpret_cast<const uint4*>(feat2 + ((size_t)s0 << 6) + fl * 4);
            uint4 v1 = *reinterpret_cast<const uint4*>(feat2 + ((size_t)s1 << 6) + fl * 4);
            a0 += w0 * b2f_lo(v0.x); a1 += w0 * b2f_hi(v0.x);
            a2 += w0 * b2f_lo(v0.y); a3 += w0 * b2f_hi(v0.y);
            a4 += w0 * b2f_lo(v0.z); a5 += w0 * b2f_hi(v0.z);
            a6 += w0 * b2f_lo(v0.w); a7 += w0 * b2f_hi(v0.w);
            a0 += w1 * b2f_lo(v1.x); a1 += w1 * b2f_hi(v1.x);
            a2 += w1 * b2f_lo(v1.y); a3 += w1 * b2f_hi(v1.y);
            a4 += w1 * b2f_lo(v1.z); a5 += w1 * b2f_hi(v1.z);
            a6 += w1 * b2f_lo(v1.w); a7 += w1 * b2f_hi(v1.w);
        }
        // fold edge groups: xor 16 then 32
        a0 += __shfl_xor(a0, 16, 64); a1 += __shfl_xor(a1, 16, 64);
        a2 += __shfl_xor(a2, 16, 64); a3 += __shfl_xor(a3, 16, 64);
        a4 += __shfl_xor(a4, 16, 64); a5 += __shfl_xor(a5, 16, 64);
        a6 += __shfl_xor(a6, 16, 64); a7 += __shfl_xor(a7, 16, 64);
        a0 += __shfl_xor(a0, 32, 64); a1 += __shfl_xor(a1, 32, 64);
        a2 += __shfl_xor(a2, 32, 64); a3 += __shfl_xor(a3, 32, 64);
        a4 += __shfl_xor(a4, 32, 64); a5 += __shfl_xor(a5, 32, 64);
        a6 += __shfl_xor(a6, 32, 64); a7 += __shfl_xor(a7, 32, 64);

        float dnv = dls[dl];
        float inv = dnv > 0.f ? 1.f / dnv : 0.f;       // isolated node -> 0
        float g0 = a0 * inv + bA[0], g1 = a1 * inv + bA[1];
        float g2 = a2 * inv + bA[2], g3 = a3 * inv + bA[3];
        float g4 = a4 * inv + bB[0], g5 = a5 * inv + bB[1];
        float g6 = a6 * inv + bB[2], g7 = a7 * inv + bB[3];
        g0 = g0 > 0.f ? g0 : 0.01f * g0; g1 = g1 > 0.f ? g1 : 0.01f * g1;
        g2 = g2 > 0.f ? g2 : 0.01f * g2; g3 = g3 > 0.f ? g3 : 0.01f * g3;
        g4 = g4 > 0.f ? g4 : 0.01f * g4; g5 = g5 > 0.f ? g5 : 0.01f * g5;
        g6 = g6 > 0.f ? g6 : 0.01f * g6; g7 = g7 > 0.f ? g7 : 0.01f * g7;
        if (eg == 0) {
            sg[dl * 68 + fl * 4 + 0] = (unsigned)f2b(g0) | ((unsigned)f2b(g1) << 16);
            sg[dl * 68 + fl * 4 + 1] = (unsigned)f2b(g2) | ((unsigned)f2b(g3) << 16);
            sg[dl * 68 + fl * 4 + 2] = (unsigned)f2b(g4) | ((unsigned)f2b(g5) << 16);
            sg[dl * 68 + fl * 4 + 3] = (unsigned)f2b(g6) | ((unsigned)f2b(g7) << 16);
        }
    }
    __syncthreads();

    // ---- phase C: 16x64 output GEMM ----
    int col = lane & 15, quad = lane >> 4;
    int nt = wave;
    f32x4 acc = {};
#pragma unroll
    for (int kt = 0; kt < 4; kt++) {
        bf16x8 a = *reinterpret_cast<const bf16x8*>(&sg[col * 68 + kt * 16 + quad * 4]);
        bf16x8 bf = *reinterpret_cast<const bf16x8*>(pWl + ((kt * 4 + nt) * 64 + lane) * 8);
        acc = __builtin_amdgcn_mfma_f32_16x16x32_bf16(a, bf, acc, 0, 0, 0);
    }
#pragma unroll
    for (int reg = 0; reg < 4; reg++)
        out[(size_t)(nb + quad * 4 + reg) * OUTF + nt * 16 + col] = acc[reg];
}

// ---------------------------------------------------------------------------
extern "C" void kernel_launch(void* const* d_in, const int* in_sizes, int n_in,
                              void* d_out, int out_size, void* d_ws, size_t ws_size,
                              hipStream_t stream) {
    const float* x      = (const float*)d_in[0];   // [50000,256] fp32
    const int*   src    = (const int*)d_in[1];     // [800000] int32
    const int*   dst    = (const int*)d_in[2];     // [800000] int32
    const float* Wg     = (const float*)d_in[3];   // [256,128] fp32
    const float* attn_l = (const float*)d_in[4];   // [128]
    const float* attn_r = (const float*)d_in[5];   // [128]
    const float* bias   = (const float*)d_in[6];   // [128]
    const float* Wl     = (const float*)d_in[7];   // [64,128] fp32
    float* out          = (float*)d_out;           // [50000,64] fp32

    char* ws = (char*)d_ws;
    size_t off = 0;
    auto alloc = [&](size_t b) { size_t r = off; off += (b + 255) & ~(size_t)255; return r; };
    size_t pwgOff  = alloc((size_t)8 * 8 * 64 * 8 * 2);     // 64 KB
    size_t pwlOff  = alloc((size_t)4 * 4 * 64 * 8 * 2);     // 16 KB
    size_t featOff = alloc((size_t)NNODES * HID * 2);       // 12.8 MB bf16 feat
    size_t elOff   = alloc((size_t)NNODES * 4);
    size_t erOff   = alloc((size_t)NNODES * 4);
    size_t pairOff = alloc((size_t)NBKT * BCAP * 8);        // 8.0 MB bucket regions
    size_t bcntOff = alloc((size_t)NBKT * 4);

    u16*      pWg   = (u16*)(ws + pwgOff);
    u16*      pWl   = (u16*)(ws + pwlOff);
    unsigned* feat2 = (unsigned*)(ws + featOff);
    float*    el    = (float*)(ws + elOff);
    float*    er    = (float*)(ws + erOff);
    u64*      pairs = (u64*)(ws + pairOff);
    int*      bcnt  = (int*)(ws + bcntOff);

    pack0<<<21, 256, 0, stream>>>(Wg, Wl, pWg, pWl, bcnt);
    k_mega<<<GB + PA_NB, 256, 0, stream>>>(x, pWg, attn_l, attn_r, feat2, el, er,
                                           src, dst, bcnt, pairs);
    k_aggslim<<<AGB, 256, 0, stream>>>(pairs, bcnt, el, er, feat2, bias,
                                       pWl, out);
}

// Round 12
// 159.527 us; speedup vs baseline: 1.1095x; 1.0506x over previous
//
#include <hip/hip_runtime.h>
#include <hip/hip_bf16.h>

// GAT layer on MI355X. Round 27: cut scan redundancy 4x on the AGG side
// (not the partition side). Evidence: r7 (64-node buckets) pushed k_aggslim
// out of the top-5 (scan redundancy /4 worked) but its 782-bin partition
// cost more than it saved; r11 showed wide loads hurt (latency regime wants
// MANY outstanding misses). So: agg block = 1024 threads / 64 nodes
// (16 waves) scanning the coarse 256-node window ONCE -> window read by 4
// blocks not 16. Gather wave-parallelism preserved: 784 x 16 = 12.5K waves
// == r6's 3136 x 4. Phase B per-wave code byte-identical to r6 (proven best
// shape). LDS ~50KB -> 2 blocks/CU = 32 waves/CU (full occupancy).
// k_mega / pack0 byte-identical to round 6. 3 dispatches.

#define NNODES 50000
#define NEDGES 800000
#define IN_F   256
#define HID    128
#define OUTF   64

#define PA_EPT   8
#define PA_EDGES (256 * PA_EPT)                          // 2048 edges/block
#define PA_NB    ((NEDGES + PA_EDGES - 1) / PA_EDGES)    // 391 blocks
#define NBKT     ((NNODES + 255) / 256)                  // 196 buckets (dst>>8)
#define BCAP     5120                                    // bucket capacity (lam=4082)
#define NSTRIP   (NNODES / 16)                           // 3125 strips
#define GB       ((NSTRIP + 3) / 4)                      // 782 gemm blocks

#define AGN      64                                      // nodes per agg block
#define AGSLOT   64                                      // per-node LDS slot cap (max deg ~45)
#define AGB      784                                     // 8 * 98 agg blocks (>= 782)

typedef unsigned short u16;
typedef unsigned long long u64;
typedef __bf16 bf16x8 __attribute__((ext_vector_type(8)));
typedef float  f32x4  __attribute__((ext_vector_type(4)));

__device__ __forceinline__ u16 f2b(float f) {
    union { float f; unsigned u; } v; v.f = f;
    unsigned u = v.u;
    return (u16)((u + 0x7fffu + ((u >> 16) & 1u)) >> 16);  // RNE fp32->bf16
}
__device__ __forceinline__ float b2f_lo(unsigned v) {
    union { unsigned u; float f; } c; c.u = (v & 0xffffu) << 16; return c.f;
}
__device__ __forceinline__ float b2f_hi(unsigned v) {
    union { unsigned u; float f; } c; c.u = v & 0xffff0000u; return c.f;
}
__device__ __forceinline__ float lrelu02_exp(float t) {
    t = t > 0.f ? t : 0.2f * t;                        // leaky_relu(0.2)
    return __expf(t);
}

// ---------------------------------------------------------------------------
// pack0: blocks 0..15 pack W_gat, 16..19 pack W_lin, 20 zeroes bcnt.
__global__ __launch_bounds__(256) void pack0(const float* __restrict__ Wg,
                                             const float* __restrict__ Wl,
                                             u16* __restrict__ pWg,
                                             u16* __restrict__ pWl,
                                             int* __restrict__ bcnt) {
    int blk = blockIdx.x, tid = threadIdx.x;
    if (blk < 16) {
        int t = blk * 256 + tid;
        int lane = t & 63, tile = t >> 6;
        int nt = tile & 7, kt = tile >> 3;
        int col = lane & 15, quad = lane >> 4;
        int krow = kt * 32 + quad * 8;
        int ncol = nt * 16 + col;
#pragma unroll
        for (int j = 0; j < 8; j++) pWg[t * 8 + j] = f2b(Wg[(krow + j) * HID + ncol]);
    } else if (blk < 20) {
        int t = (blk - 16) * 256 + tid;
        int lane = t & 63, tile = t >> 6;
        int nt = tile & 3, kt = tile >> 2;
        int col = lane & 15, quad = lane >> 4;
        int o  = nt * 16 + col;
        int k0 = kt * 32 + quad * 8;
#pragma unroll
        for (int j = 0; j < 8; j++) pWl[t * 8 + j] = f2b(Wl[o * HID + k0 + j]);
    } else {
        if (tid < NBKT) bcnt[tid] = 0;
    }
}

// ---------------------------------------------------------------------------
// k_mega: blocks [0,GB) = feat GEMM (1 strip/wave, 16 hoisted x-loads,
// fused el/er epilogue); blocks [GB, GB+PA_NB) = edge partition into 196
// bucket regions. Byte-identical to round 6.
__global__ __launch_bounds__(256) void k_mega(
        const float* __restrict__ x, const u16* __restrict__ pWg,
        const float* __restrict__ al_, const float* __restrict__ ar_,
        unsigned* __restrict__ feat2, float* __restrict__ el, float* __restrict__ er,
        const int* __restrict__ src, const int* __restrict__ dst,
        int* __restrict__ bcnt, u64* __restrict__ pairs) {
    __shared__ u64 smemU[21504 / 8];
    char* smem = (char*)smemU;
    int blk = blockIdx.x, tid = threadIdx.x;

    if (blk < GB) {
        // ---- feat GEMM path (no LDS use) ----
        int wave = tid >> 6, lane = tid & 63;
        int strip = blk * 4 + wave;
        if (strip >= NSTRIP) return;
        int m0 = strip * 16;
        int col = lane & 15, quad = lane >> 4;

        // hoist ALL x loads for this strip: 16 independent 16B loads/lane
        f32x4 xa[16];
        const float* xr = x + (size_t)(m0 + col) * IN_F + quad * 8;
#pragma unroll
        for (int kt = 0; kt < 8; kt++) {
            xa[2 * kt]     = *reinterpret_cast<const f32x4*>(xr + kt * 32);
            xa[2 * kt + 1] = *reinterpret_cast<const f32x4*>(xr + kt * 32 + 4);
        }
        bf16x8 av[8];
#pragma unroll
        for (int kt = 0; kt < 8; kt++)
#pragma unroll
            for (int j = 0; j < 4; j++) {
                av[kt][j]     = (__bf16)xa[2 * kt][j];
                av[kt][4 + j] = (__bf16)xa[2 * kt + 1][j];
            }

        f32x4 acc[8] = {};
#pragma unroll
        for (int kt = 0; kt < 8; kt++)
#pragma unroll
            for (int nt = 0; nt < 8; nt++) {
                bf16x8 b = *reinterpret_cast<const bf16x8*>(pWg + ((kt * 8 + nt) * 64 + lane) * 8);
                acc[nt] = __builtin_amdgcn_mfma_f32_16x16x32_bf16(av[kt], b, acc[nt], 0, 0, 0);
            }

        // epilogue: el/er dot products + bf16 feat store
        float pl[4] = {0, 0, 0, 0}, pr[4] = {0, 0, 0, 0};
#pragma unroll
        for (int nt = 0; nt < 8; nt++) {
            float alv = al_[nt * 16 + col], arv = ar_[nt * 16 + col];
#pragma unroll
            for (int reg = 0; reg < 4; reg++) {
                pl[reg] += acc[nt][reg] * alv;
                pr[reg] += acc[nt][reg] * arv;
            }
        }
#pragma unroll
        for (int m = 1; m < 16; m <<= 1)
#pragma unroll
            for (int reg = 0; reg < 4; reg++) {
                pl[reg] += __shfl_xor(pl[reg], m, 64);
                pr[reg] += __shfl_xor(pr[reg], m, 64);
            }
        if (col == 0) {
#pragma unroll
            for (int reg = 0; reg < 4; reg++) {
                el[m0 + quad * 4 + reg] = pl[reg];
                er[m0 + quad * 4 + reg] = pr[reg];
            }
        }
#pragma unroll
        for (int nt = 0; nt < 8; nt++)
#pragma unroll
            for (int reg = 0; reg < 4; reg++) {
                u16* fp = (u16*)feat2;
                fp[(size_t)(m0 + quad * 4 + reg) * HID + nt * 16 + col] = f2b(acc[nt][reg]);
            }
        return;
    }

    // ---- edge partition path ----
    int* hist    = (int*)smem;                         // 256 ints (196 used)
    int* binbase = hist + 256;
    int* gbase   = binbase + 256;
    int* fill    = gbase + 256;
    int* stmp    = fill + 256;                         // 256 ints -> 5120 B
    u64* spair   = (u64*)(smem + 5120);                // 2048 * 8 = 16384 B

    int e0 = (blk - GB) * PA_EDGES;
    int cnt = NEDGES - e0; if (cnt > PA_EDGES) cnt = PA_EDGES;

    hist[tid] = 0; fill[tid] = 0;
    __syncthreads();

    int es[PA_EPT], ed[PA_EPT];
#pragma unroll
    for (int j = 0; j < PA_EPT; j++) {
        int idx = e0 + j * 256 + tid;
        if (idx < NEDGES) {
            es[j] = src[idx];
            ed[j] = dst[idx];
            atomicAdd(&hist[ed[j] >> 8], 1);
        } else ed[j] = -1;
    }
    __syncthreads();

    stmp[tid] = (tid < NBKT) ? hist[tid] : 0;
    __syncthreads();
#pragma unroll
    for (int ofs = 1; ofs < 256; ofs <<= 1) {
        int u = (tid >= ofs) ? stmp[tid - ofs] : 0;
        __syncthreads();
        stmp[tid] += u;
        __syncthreads();
    }
    if (tid < NBKT) {
        binbase[tid] = stmp[tid] - hist[tid];
        if (hist[tid] > 0)
            gbase[tid] = tid * BCAP + atomicAdd(&bcnt[tid], hist[tid]);
    }
    __syncthreads();

#pragma unroll
    for (int j = 0; j < PA_EPT; j++) {
        if (ed[j] >= 0) {
            int b = ed[j] >> 8;
            int r = atomicAdd(&fill[b], 1);
            int loc = binbase[b] + r;
            spair[loc] = ((u64)(unsigned)ed[j] << 32) | (unsigned)es[j];
        }
    }
    __syncthreads();

    for (int i = tid; i < cnt; i += 256) {
        u64 p = spair[i];
        int b = (int)(p >> 40);                        // dst>>8 from packed pair
        pairs[gbase[b] + (i - binbase[b])] = p;
    }
}

// ---------------------------------------------------------------------------
// k_agg64: one block (1024 thr, 16 waves) per 64 nodes (784 blocks,
// XCD-swizzled: a coarse bucket's 4 blocks are consecutive logicals -> one
// XCD L2). Phase A: scan the coarse 256-node window ONCE per block (4x
// redundancy, was 16x), filter to the block's 64 nodes, build 64x64-slot
// LDS lists with w inline. Phase B: round-6 8-deep wave-per-node gather
// (wave w owns nodes 4w..4w+3). Phase C: 16 waves = 4 node-tiles x 4 nt
// over the 64x64 output tile.
__global__ __launch_bounds__(1024) void k_agg64(const u64* __restrict__ pairs,
                                                const int* __restrict__ bcnt,
                                                const float* __restrict__ el,
                                                const float* __restrict__ er,
                                                const unsigned* __restrict__ feat2,
                                                const float* __restrict__ bias,
                                                const u16* __restrict__ pWl,
                                                float* __restrict__ out) {
    __shared__ int   cnt_l[AGN];
    __shared__ float erl[AGN];
    __shared__ int   ssrc[AGN * AGSLOT];               // 16 KB
    __shared__ float swgt[AGN * AGSLOT];               // 16 KB
    __shared__ unsigned sg[AGN * 68];                  // 17.4 KB

    int tid = threadIdx.x;
    int wave = tid >> 6, lane = tid & 63;
    // XCD-bijective swizzle: 784 = 8 * 98.
    int logical = (blockIdx.x & 7) * 98 + (blockIdx.x >> 3);
    int nb = logical * AGN;
    if (nb >= NNODES) return;
    int cb = logical >> 2;                             // coarse 256-node bucket

    if (tid < AGN) {
        cnt_l[tid] = 0;
        int n = nb + tid;
        erl[tid] = (n < NNODES) ? er[n] : 0.f;
    }
    __syncthreads();

    // ---- phase A: filter + attention weight + LDS list build ----
    int cntb = bcnt[cb];
    const u64* reg = pairs + (size_t)cb * BCAP;
    for (int i = tid; i < cntb; i += 1024) {
        u64 p = reg[i];
        int d = (int)(unsigned)(p >> 32);
        unsigned dl = (unsigned)(d - nb);
        if (dl < (unsigned)AGN) {
            int s = (int)(unsigned)(p & 0xffffffffu);
            float w = lrelu02_exp(el[s] + erl[dl]);
            int slot = atomicAdd(&cnt_l[dl], 1);
            if (slot < AGSLOT) {
                ssrc[dl * AGSLOT + slot] = s;
                swgt[dl * AGSLOT + slot] = w;
            }
        }
    }
    __syncthreads();

    // ---- phase B: wave-per-node gather + normalize (round-6 shape) ----
    float bl = bias[lane * 2 + 0], bh = bias[lane * 2 + 1];
    for (int i = 0; i < 4; i++) {
        int dl = wave * 4 + i;
        int cnt = cnt_l[dl]; if (cnt > AGSLOT) cnt = AGSLOT;
        const int*   ep = ssrc + dl * AGSLOT;
        const float* wp = swgt + dl * AGSLOT;

        float p0 = 0.f, p1 = 0.f, q0 = 0.f, q1 = 0.f;
        float r0 = 0.f, r1 = 0.f, t0 = 0.f, t1 = 0.f;
        float u0 = 0.f, u1 = 0.f, x0 = 0.f, x1 = 0.f;
        float y0 = 0.f, y1 = 0.f, z0 = 0.f, z1 = 0.f;
        float dn = 0.f;
        int j = 0;
        for (; j + 8 <= cnt; j += 8) {
            int4 sa = *reinterpret_cast<const int4*>(ep + j);
            int4 sb = *reinterpret_cast<const int4*>(ep + j + 4);
            float4 wa = *reinterpret_cast<const float4*>(wp + j);
            float4 wb = *reinterpret_cast<const float4*>(wp + j + 4);
            unsigned v0 = feat2[(size_t)sa.x * 64 + lane];
            unsigned v1 = feat2[(size_t)sa.y * 64 + lane];
            unsigned v2 = feat2[(size_t)sa.z * 64 + lane];
            unsigned v3 = feat2[(size_t)sa.w * 64 + lane];
            unsigned v4 = feat2[(size_t)sb.x * 64 + lane];
            unsigned v5 = feat2[(size_t)sb.y * 64 + lane];
            unsigned v6 = feat2[(size_t)sb.z * 64 + lane];
            unsigned v7 = feat2[(size_t)sb.w * 64 + lane];
            p0 += wa.x * b2f_lo(v0); p1 += wa.x * b2f_hi(v0);
            q0 += wa.y * b2f_lo(v1); q1 += wa.y * b2f_hi(v1);
            r0 += wa.z * b2f_lo(v2); r1 += wa.z * b2f_hi(v2);
            t0 += wa.w * b2f_lo(v3); t1 += wa.w * b2f_hi(v3);
            u0 += wb.x * b2f_lo(v4); u1 += wb.x * b2f_hi(v4);
            x0 += wb.y * b2f_lo(v5); x1 += wb.y * b2f_hi(v5);
            y0 += wb.z * b2f_lo(v6); y1 += wb.z * b2f_hi(v6);
            z0 += wb.w * b2f_lo(v7); z1 += wb.w * b2f_hi(v7);
            dn += ((wa.x + wa.y) + (wa.z + wa.w)) + ((wb.x + wb.y) + (wb.z + wb.w));
        }
        if (j + 4 <= cnt) {
            int4 sa = *reinterpret_cast<const int4*>(ep + j);
            float4 wa = *reinterpret_cast<const float4*>(wp + j);
            unsigned v0 = feat2[(size_t)sa.x * 64 + lane];
            unsigned v1 = feat2[(size_t)sa.y * 64 + lane];
            unsigned v2 = feat2[(size_t)sa.z * 64 + lane];
            unsigned v3 = feat2[(size_t)sa.w * 64 + lane];
            p0 += wa.x * b2f_lo(v0); p1 += wa.x * b2f_hi(v0);
            q0 += wa.y * b2f_lo(v1); q1 += wa.y * b2f_hi(v1);
            r0 += wa.z * b2f_lo(v2); r1 += wa.z * b2f_hi(v2);
            t0 += wa.w * b2f_lo(v3); t1 += wa.w * b2f_hi(v3);
            dn += (wa.x + wa.y) + (wa.z + wa.w);
            j += 4;
        }
        for (; j < cnt; j++) {
            int s = ep[j];
            float w = wp[j];
            unsigned v = feat2[(size_t)s * 64 + lane];
            p0 += w * b2f_lo(v); p1 += w * b2f_hi(v);
            dn += w;
        }
        float a0 = ((p0 + q0) + (r0 + t0)) + ((u0 + x0) + (y0 + z0));
        float a1 = ((p1 + q1) + (r1 + t1)) + ((u1 + x1) + (y1 + z1));

        float inv = dn > 0.f ? 1.f / dn : 0.f;         // isolated node -> 0
        float g0 = a0 * inv + bl;
        float g1 = a1 * inv + bh;
        g0 = g0 > 0.f ? g0 : 0.01f * g0;               // leaky_relu(0.01)
        g1 = g1 > 0.f ? g1 : 0.01f * g1;
        sg[dl * 68 + lane] = (unsigned)f2b(g0) | ((unsigned)f2b(g1) << 16);
    }
    __syncthreads();

    // ---- phase C: 64x64 output GEMM (wave = node-tile x nt) ----
    int col = lane & 15, quad = lane >> 4;
    int tile = wave >> 2;                              // node tile 0..3
    int nt = wave & 3;                                 // output col tile 0..3
    f32x4 acc = {};
#pragma unroll
    for (int kt = 0; kt < 4; kt++) {
        bf16x8 a = *reinterpret_cast<const bf16x8*>(&sg[(tile * 16 + col) * 68 + kt * 16 + quad * 4]);
        bf16x8 bf = *reinterpret_cast<const bf16x8*>(pWl + ((kt * 4 + nt) * 64 + lane) * 8);
        acc = __builtin_amdgcn_mfma_f32_16x16x32_bf16(a, bf, acc, 0, 0, 0);
    }
#pragma unroll
    for (int reg = 0; reg < 4; reg++) {
        int row = nb + tile * 16 + quad * 4 + reg;
        if (row < NNODES)
            out[(size_t)row * OUTF + nt * 16 + col] = acc[reg];
    }
}

// ---------------------------------------------------------------------------
extern "C" void kernel_launch(void* const* d_in, const int* in_sizes, int n_in,
                              void* d_out, int out_size, void* d_ws, size_t ws_size,
                              hipStream_t stream) {
    const float* x      = (const float*)d_in[0];   // [50000,256] fp32
    const int*   src    = (const int*)d_in[1];     // [800000] int32
    const int*   dst    = (const int*)d_in[2];     // [800000] int32
    const float* Wg     = (const float*)d_in[3];   // [256,128] fp32
    const float* attn_l = (const float*)d_in[4];   // [128]
    const float* attn_r = (const float*)d_in[5];   // [128]
    const float* bias   = (const float*)d_in[6];   // [128]
    const float* Wl     = (const float*)d_in[7];   // [64,128] fp32
    float* out          = (float*)d_out;           // [50000,64] fp32

    char* ws = (char*)d_ws;
    size_t off = 0;
    auto alloc = [&](size_t b) { size_t r = off; off += (b + 255) & ~(size_t)255; return r; };
    size_t pwgOff  = alloc((size_t)8 * 8 * 64 * 8 * 2);     // 64 KB
    size_t pwlOff  = alloc((size_t)4 * 4 * 64 * 8 * 2);     // 16 KB
    size_t featOff = alloc((size_t)NNODES * HID * 2);       // 12.8 MB bf16 feat
    size_t elOff   = alloc((size_t)NNODES * 4);
    size_t erOff   = alloc((size_t)NNODES * 4);
    size_t pairOff = alloc((size_t)NBKT * BCAP * 8);        // 8.0 MB bucket regions
    size_t bcntOff = alloc((size_t)NBKT * 4);

    u16*      pWg   = (u16*)(ws + pwgOff);
    u16*      pWl   = (u16*)(ws + pwlOff);
    unsigned* feat2 = (unsigned*)(ws + featOff);
    float*    el    = (float*)(ws + elOff);
    float*    er    = (float*)(ws + erOff);
    u64*      pairs = (u64*)(ws + pairOff);
    int*      bcnt  = (int*)(ws + bcntOff);

    pack0<<<21, 256, 0, stream>>>(Wg, Wl, pWg, pWl, bcnt);
    k_mega<<<GB + PA_NB, 256, 0, stream>>>(x, pWg, attn_l, attn_r, feat2, el, er,
                                           src, dst, bcnt, pairs);
    k_agg64<<<AGB, 1024, 0, stream>>>(pairs, bcnt, el, er, feat2, bias,
                                      pWl, out);
}

// Round 13
// 158.128 us; speedup vs baseline: 1.1194x; 1.0088x over previous
//
#include <hip/hip_runtime.h>
#include <hip/hip_bf16.h>

// GAT layer on MI355X. Round 28: FORCE load liveness with asm use-barriers.
// Round-12 = best (159.5; k_agg64 42.4). The never-moving counter across 12
// rounds: VGPR 32-36 on every kernel -- the allocator rolls load bursts into
// ~2-reg loops (r3 source hoist: no effect; r10 launch_bounds: no effect).
// asm volatile("" :: "v"(x)...) demands all named values be simultaneously
// VGPR-resident -> only sane schedule = issue all loads, one waitcnt, then
// compute. Applied to (1) k_mega's 16 x-loads (grid is 4.6 blk/CU, so VGPR
// up to ~110 costs zero real occupancy), (2) k_agg64 phase-B's 8 gather
// dwords (VGPR ~64 still fits 2 blocks/CU = 32 waves).
// Everything else byte-identical to round 12. 3 dispatches.

#define NNODES 50000
#define NEDGES 800000
#define IN_F   256
#define HID    128
#define OUTF   64

#define PA_EPT   8
#define PA_EDGES (256 * PA_EPT)                          // 2048 edges/block
#define PA_NB    ((NEDGES + PA_EDGES - 1) / PA_EDGES)    // 391 blocks
#define NBKT     ((NNODES + 255) / 256)                  // 196 buckets (dst>>8)
#define BCAP     5120                                    // bucket capacity (lam=4082)
#define NSTRIP   (NNODES / 16)                           // 3125 strips
#define GB       ((NSTRIP + 3) / 4)                      // 782 gemm blocks

#define AGN      64                                      // nodes per agg block
#define AGSLOT   64                                      // per-node LDS slot cap (max deg ~45)
#define AGB      784                                     // 8 * 98 agg blocks (>= 782)

typedef unsigned short u16;
typedef unsigned long long u64;
typedef __bf16 bf16x8 __attribute__((ext_vector_type(8)));
typedef float  f32x4  __attribute__((ext_vector_type(4)));

__device__ __forceinline__ u16 f2b(float f) {
    union { float f; unsigned u; } v; v.f = f;
    unsigned u = v.u;
    return (u16)((u + 0x7fffu + ((u >> 16) & 1u)) >> 16);  // RNE fp32->bf16
}
__device__ __forceinline__ float b2f_lo(unsigned v) {
    union { unsigned u; float f; } c; c.u = (v & 0xffffu) << 16; return c.f;
}
__device__ __forceinline__ float b2f_hi(unsigned v) {
    union { unsigned u; float f; } c; c.u = v & 0xffff0000u; return c.f;
}
__device__ __forceinline__ float lrelu02_exp(float t) {
    t = t > 0.f ? t : 0.2f * t;                        // leaky_relu(0.2)
    return __expf(t);
}

// ---------------------------------------------------------------------------
// pack0: blocks 0..15 pack W_gat, 16..19 pack W_lin, 20 zeroes bcnt.
__global__ __launch_bounds__(256) void pack0(const float* __restrict__ Wg,
                                             const float* __restrict__ Wl,
                                             u16* __restrict__ pWg,
                                             u16* __restrict__ pWl,
                                             int* __restrict__ bcnt) {
    int blk = blockIdx.x, tid = threadIdx.x;
    if (blk < 16) {
        int t = blk * 256 + tid;
        int lane = t & 63, tile = t >> 6;
        int nt = tile & 7, kt = tile >> 3;
        int col = lane & 15, quad = lane >> 4;
        int krow = kt * 32 + quad * 8;
        int ncol = nt * 16 + col;
#pragma unroll
        for (int j = 0; j < 8; j++) pWg[t * 8 + j] = f2b(Wg[(krow + j) * HID + ncol]);
    } else if (blk < 20) {
        int t = (blk - 16) * 256 + tid;
        int lane = t & 63, tile = t >> 6;
        int nt = tile & 3, kt = tile >> 2;
        int col = lane & 15, quad = lane >> 4;
        int o  = nt * 16 + col;
        int k0 = kt * 32 + quad * 8;
#pragma unroll
        for (int j = 0; j < 8; j++) pWl[t * 8 + j] = f2b(Wl[o * HID + k0 + j]);
    } else {
        if (tid < NBKT) bcnt[tid] = 0;
    }
}

// ---------------------------------------------------------------------------
// k_mega: blocks [0,GB) = feat GEMM (1 strip/wave, 16 x-loads pinned live
// via asm use-barrier, fused el/er epilogue); blocks [GB, GB+PA_NB) = edge
// partition into 196 bucket regions.
__global__ __launch_bounds__(256) void k_mega(
        const float* __restrict__ x, const u16* __restrict__ pWg,
        const float* __restrict__ al_, const float* __restrict__ ar_,
        unsigned* __restrict__ feat2, float* __restrict__ el, float* __restrict__ er,
        const int* __restrict__ src, const int* __restrict__ dst,
        int* __restrict__ bcnt, u64* __restrict__ pairs) {
    __shared__ u64 smemU[21504 / 8];
    char* smem = (char*)smemU;
    int blk = blockIdx.x, tid = threadIdx.x;

    if (blk < GB) {
        // ---- feat GEMM path (no LDS use) ----
        int wave = tid >> 6, lane = tid & 63;
        int strip = blk * 4 + wave;
        if (strip >= NSTRIP) return;
        int m0 = strip * 16;
        int col = lane & 15, quad = lane >> 4;

        // hoist ALL x loads for this strip: 16 independent 16B loads/lane
        f32x4 xa[16];
        const float* xr = x + (size_t)(m0 + col) * IN_F + quad * 8;
#pragma unroll
        for (int kt = 0; kt < 8; kt++) {
            xa[2 * kt]     = *reinterpret_cast<const f32x4*>(xr + kt * 32);
            xa[2 * kt + 1] = *reinterpret_cast<const f32x4*>(xr + kt * 32 + 4);
        }
        // pin all 16 loads simultaneously resident -> burst issue, one wait
        asm volatile("" :: "v"(xa[0]), "v"(xa[1]), "v"(xa[2]), "v"(xa[3]),
                           "v"(xa[4]), "v"(xa[5]), "v"(xa[6]), "v"(xa[7]),
                           "v"(xa[8]), "v"(xa[9]), "v"(xa[10]), "v"(xa[11]),
                           "v"(xa[12]), "v"(xa[13]), "v"(xa[14]), "v"(xa[15]));
        bf16x8 av[8];
#pragma unroll
        for (int kt = 0; kt < 8; kt++)
#pragma unroll
            for (int j = 0; j < 4; j++) {
                av[kt][j]     = (__bf16)xa[2 * kt][j];
                av[kt][4 + j] = (__bf16)xa[2 * kt + 1][j];
            }

        f32x4 acc[8] = {};
#pragma unroll
        for (int kt = 0; kt < 8; kt++)
#pragma unroll
            for (int nt = 0; nt < 8; nt++) {
                bf16x8 b = *reinterpret_cast<const bf16x8*>(pWg + ((kt * 8 + nt) * 64 + lane) * 8);
                acc[nt] = __builtin_amdgcn_mfma_f32_16x16x32_bf16(av[kt], b, acc[nt], 0, 0, 0);
            }

        // epilogue: el/er dot products + bf16 feat store
        float pl[4] = {0, 0, 0, 0}, pr[4] = {0, 0, 0, 0};
#pragma unroll
        for (int nt = 0; nt < 8; nt++) {
            float alv = al_[nt * 16 + col], arv = ar_[nt * 16 + col];
#pragma unroll
            for (int reg = 0; reg < 4; reg++) {
                pl[reg] += acc[nt][reg] * alv;
                pr[reg] += acc[nt][reg] * arv;
            }
        }
#pragma unroll
        for (int m = 1; m < 16; m <<= 1)
#pragma unroll
            for (int reg = 0; reg < 4; reg++) {
                pl[reg] += __shfl_xor(pl[reg], m, 64);
                pr[reg] += __shfl_xor(pr[reg], m, 64);
            }
        if (col == 0) {
#pragma unroll
            for (int reg = 0; reg < 4; reg++) {
                el[m0 + quad * 4 + reg] = pl[reg];
                er[m0 + quad * 4 + reg] = pr[reg];
            }
        }
#pragma unroll
        for (int nt = 0; nt < 8; nt++)
#pragma unroll
            for (int reg = 0; reg < 4; reg++) {
                u16* fp = (u16*)feat2;
                fp[(size_t)(m0 + quad * 4 + reg) * HID + nt * 16 + col] = f2b(acc[nt][reg]);
            }
        return;
    }

    // ---- edge partition path ----
    int* hist    = (int*)smem;                         // 256 ints (196 used)
    int* binbase = hist + 256;
    int* gbase   = binbase + 256;
    int* fill    = gbase + 256;
    int* stmp    = fill + 256;                         // 256 ints -> 5120 B
    u64* spair   = (u64*)(smem + 5120);                // 2048 * 8 = 16384 B

    int e0 = (blk - GB) * PA_EDGES;
    int cnt = NEDGES - e0; if (cnt > PA_EDGES) cnt = PA_EDGES;

    hist[tid] = 0; fill[tid] = 0;
    __syncthreads();

    int es[PA_EPT], ed[PA_EPT];
#pragma unroll
    for (int j = 0; j < PA_EPT; j++) {
        int idx = e0 + j * 256 + tid;
        if (idx < NEDGES) {
            es[j] = src[idx];
            ed[j] = dst[idx];
            atomicAdd(&hist[ed[j] >> 8], 1);
        } else ed[j] = -1;
    }
    __syncthreads();

    stmp[tid] = (tid < NBKT) ? hist[tid] : 0;
    __syncthreads();
#pragma unroll
    for (int ofs = 1; ofs < 256; ofs <<= 1) {
        int u = (tid >= ofs) ? stmp[tid - ofs] : 0;
        __syncthreads();
        stmp[tid] += u;
        __syncthreads();
    }
    if (tid < NBKT) {
        binbase[tid] = stmp[tid] - hist[tid];
        if (hist[tid] > 0)
            gbase[tid] = tid * BCAP + atomicAdd(&bcnt[tid], hist[tid]);
    }
    __syncthreads();

#pragma unroll
    for (int j = 0; j < PA_EPT; j++) {
        if (ed[j] >= 0) {
            int b = ed[j] >> 8;
            int r = atomicAdd(&fill[b], 1);
            int loc = binbase[b] + r;
            spair[loc] = ((u64)(unsigned)ed[j] << 32) | (unsigned)es[j];
        }
    }
    __syncthreads();

    for (int i = tid; i < cnt; i += 256) {
        u64 p = spair[i];
        int b = (int)(p >> 40);                        // dst>>8 from packed pair
        pairs[gbase[b] + (i - binbase[b])] = p;
    }
}

// ---------------------------------------------------------------------------
// k_agg64: one block (1024 thr, 16 waves) per 64 nodes (784 blocks,
// XCD-swizzled). Phase A: scan the coarse 256-node window once per block,
// filter, build 64x64-slot LDS lists with w inline. Phase B: 8-deep
// wave-per-node gather with the 8 dwords pinned live via asm use-barrier.
// Phase C: 16 waves = 4 node-tiles x 4 nt over the 64x64 output tile.
__global__ __launch_bounds__(1024) void k_agg64(const u64* __restrict__ pairs,
                                                const int* __restrict__ bcnt,
                                                const float* __restrict__ el,
                                                const float* __restrict__ er,
                                                const unsigned* __restrict__ feat2,
                                                const float* __restrict__ bias,
                                                const u16* __restrict__ pWl,
                                                float* __restrict__ out) {
    __shared__ int   cnt_l[AGN];
    __shared__ float erl[AGN];
    __shared__ int   ssrc[AGN * AGSLOT];               // 16 KB
    __shared__ float swgt[AGN * AGSLOT];               // 16 KB
    __shared__ unsigned sg[AGN * 68];                  // 17.4 KB

    int tid = threadIdx.x;
    int wave = tid >> 6, lane = tid & 63;
    // XCD-bijective swizzle: 784 = 8 * 98.
    int logical = (blockIdx.x & 7) * 98 + (blockIdx.x >> 3);
    int nb = logical * AGN;
    if (nb >= NNODES) return;
    int cb = logical >> 2;                             // coarse 256-node bucket

    if (tid < AGN) {
        cnt_l[tid] = 0;
        int n = nb + tid;
        erl[tid] = (n < NNODES) ? er[n] : 0.f;
    }
    __syncthreads();

    // ---- phase A: filter + attention weight + LDS list build ----
    int cntb = bcnt[cb];
    const u64* reg = pairs + (size_t)cb * BCAP;
    for (int i = tid; i < cntb; i += 1024) {
        u64 p = reg[i];
        int d = (int)(unsigned)(p >> 32);
        unsigned dl = (unsigned)(d - nb);
        if (dl < (unsigned)AGN) {
            int s = (int)(unsigned)(p & 0xffffffffu);
            float w = lrelu02_exp(el[s] + erl[dl]);
            int slot = atomicAdd(&cnt_l[dl], 1);
            if (slot < AGSLOT) {
                ssrc[dl * AGSLOT + slot] = s;
                swgt[dl * AGSLOT + slot] = w;
            }
        }
    }
    __syncthreads();

    // ---- phase B: wave-per-node gather + normalize ----
    float bl = bias[lane * 2 + 0], bh = bias[lane * 2 + 1];
    for (int i = 0; i < 4; i++) {
        int dl = wave * 4 + i;
        int cnt = cnt_l[dl]; if (cnt > AGSLOT) cnt = AGSLOT;
        const int*   ep = ssrc + dl * AGSLOT;
        const float* wp = swgt + dl * AGSLOT;

        float p0 = 0.f, p1 = 0.f, q0 = 0.f, q1 = 0.f;
        float r0 = 0.f, r1 = 0.f, t0 = 0.f, t1 = 0.f;
        float u0 = 0.f, u1 = 0.f, x0 = 0.f, x1 = 0.f;
        float y0 = 0.f, y1 = 0.f, z0 = 0.f, z1 = 0.f;
        float dn = 0.f;
        int j = 0;
        for (; j + 8 <= cnt; j += 8) {
            int4 sa = *reinterpret_cast<const int4*>(ep + j);
            int4 sb = *reinterpret_cast<const int4*>(ep + j + 4);
            float4 wa = *reinterpret_cast<const float4*>(wp + j);
            float4 wb = *reinterpret_cast<const float4*>(wp + j + 4);
            unsigned v0 = feat2[(size_t)sa.x * 64 + lane];
            unsigned v1 = feat2[(size_t)sa.y * 64 + lane];
            unsigned v2 = feat2[(size_t)sa.z * 64 + lane];
            unsigned v3 = feat2[(size_t)sa.w * 64 + lane];
            unsigned v4 = feat2[(size_t)sb.x * 64 + lane];
            unsigned v5 = feat2[(size_t)sb.y * 64 + lane];
            unsigned v6 = feat2[(size_t)sb.z * 64 + lane];
            unsigned v7 = feat2[(size_t)sb.w * 64 + lane];
            // pin all 8 gather results simultaneously resident
            asm volatile("" :: "v"(v0), "v"(v1), "v"(v2), "v"(v3),
                               "v"(v4), "v"(v5), "v"(v6), "v"(v7));
            p0 += wa.x * b2f_lo(v0); p1 += wa.x * b2f_hi(v0);
            q0 += wa.y * b2f_lo(v1); q1 += wa.y * b2f_hi(v1);
            r0 += wa.z * b2f_lo(v2); r1 += wa.z * b2f_hi(v2);
            t0 += wa.w * b2f_lo(v3); t1 += wa.w * b2f_hi(v3);
            u0 += wb.x * b2f_lo(v4); u1 += wb.x * b2f_hi(v4);
            x0 += wb.y * b2f_lo(v5); x1 += wb.y * b2f_hi(v5);
            y0 += wb.z * b2f_lo(v6); y1 += wb.z * b2f_hi(v6);
            z0 += wb.w * b2f_lo(v7); z1 += wb.w * b2f_hi(v7);
            dn += ((wa.x + wa.y) + (wa.z + wa.w)) + ((wb.x + wb.y) + (wb.z + wb.w));
        }
        if (j + 4 <= cnt) {
            int4 sa = *reinterpret_cast<const int4*>(ep + j);
            float4 wa = *reinterpret_cast<const float4*>(wp + j);
            unsigned v0 = feat2[(size_t)sa.x * 64 + lane];
            unsigned v1 = feat2[(size_t)sa.y * 64 + lane];
            unsigned v2 = feat2[(size_t)sa.z * 64 + lane];
            unsigned v3 = feat2[(size_t)sa.w * 64 + lane];
            asm volatile("" :: "v"(v0), "v"(v1), "v"(v2), "v"(v3));
            p0 += wa.x * b2f_lo(v0); p1 += wa.x * b2f_hi(v0);
            q0 += wa.y * b2f_lo(v1); q1 += wa.y * b2f_hi(v1);
            r0 += wa.z * b2f_lo(v2); r1 += wa.z * b2f_hi(v2);
            t0 += wa.w * b2f_lo(v3); t1 += wa.w * b2f_hi(v3);
            dn += (wa.x + wa.y) + (wa.z + wa.w);
            j += 4;
        }
        for (; j < cnt; j++) {
            int s = ep[j];
            float w = wp[j];
            unsigned v = feat2[(size_t)s * 64 + lane];
            p0 += w * b2f_lo(v); p1 += w * b2f_hi(v);
            dn += w;
        }
        float a0 = ((p0 + q0) + (r0 + t0)) + ((u0 + x0) + (y0 + z0));
        float a1 = ((p1 + q1) + (r1 + t1)) + ((u1 + x1) + (y1 + z1));

        float inv = dn > 0.f ? 1.f / dn : 0.f;         // isolated node -> 0
        float g0 = a0 * inv + bl;
        float g1 = a1 * inv + bh;
        g0 = g0 > 0.f ? g0 : 0.01f * g0;               // leaky_relu(0.01)
        g1 = g1 > 0.f ? g1 : 0.01f * g1;
        sg[dl * 68 + lane] = (unsigned)f2b(g0) | ((unsigned)f2b(g1) << 16);
    }
    __syncthreads();

    // ---- phase C: 64x64 output GEMM (wave = node-tile x nt) ----
    int col = lane & 15, quad = lane >> 4;
    int tile = wave >> 2;                              // node tile 0..3
    int nt = wave & 3;                                 // output col tile 0..3
    f32x4 acc = {};
#pragma unroll
    for (int kt = 0; kt < 4; kt++) {
        bf16x8 a = *reinterpret_cast<const bf16x8*>(&sg[(tile * 16 + col) * 68 + kt * 16 + quad * 4]);
        bf16x8 bf = *reinterpret_cast<const bf16x8*>(pWl + ((kt * 4 + nt) * 64 + lane) * 8);
        acc = __builtin_amdgcn_mfma_f32_16x16x32_bf16(a, bf, acc, 0, 0, 0);
    }
#pragma unroll
    for (int reg = 0; reg < 4; reg++) {
        int row = nb + tile * 16 + quad * 4 + reg;
        if (row < NNODES)
            out[(size_t)row * OUTF + nt * 16 + col] = acc[reg];
    }
}

// ---------------------------------------------------------------------------
extern "C" void kernel_launch(void* const* d_in, const int* in_sizes, int n_in,
                              void* d_out, int out_size, void* d_ws, size_t ws_size,
                              hipStream_t stream) {
    const float* x      = (const float*)d_in[0];   // [50000,256] fp32
    const int*   src    = (const int*)d_in[1];     // [800000] int32
    const int*   dst    = (const int*)d_in[2];     // [800000] int32
    const float* Wg     = (const float*)d_in[3];   // [256,128] fp32
    const float* attn_l = (const float*)d_in[4];   // [128]
    const float* attn_r = (const float*)d_in[5];   // [128]
    const float* bias   = (const float*)d_in[6];   // [128]
    const float* Wl     = (const float*)d_in[7];   // [64,128] fp32
    float* out          = (float*)d_out;           // [50000,64] fp32

    char* ws = (char*)d_ws;
    size_t off = 0;
    auto alloc = [&](size_t b) { size_t r = off; off += (b + 255) & ~(size_t)255; return r; };
    size_t pwgOff  = alloc((size_t)8 * 8 * 64 * 8 * 2);     // 64 KB
    size_t pwlOff  = alloc((size_t)4 * 4 * 64 * 8 * 2);     // 16 KB
    size_t featOff = alloc((size_t)NNODES * HID * 2);       // 12.8 MB bf16 feat
    size_t elOff   = alloc((size_t)NNODES * 4);
    size_t erOff   = alloc((size_t)NNODES * 4);
    size_t pairOff = alloc((size_t)NBKT * BCAP * 8);        // 8.0 MB bucket regions
    size_t bcntOff = alloc((size_t)NBKT * 4);

    u16*      pWg   = (u16*)(ws + pwgOff);
    u16*      pWl   = (u16*)(ws + pwlOff);
    unsigned* feat2 = (unsigned*)(ws + featOff);
    float*    el    = (float*)(ws + elOff);
    float*    er    = (float*)(ws + erOff);
    u64*      pairs = (u64*)(ws + pairOff);
    int*      bcnt  = (int*)(ws + bcntOff);

    pack0<<<21, 256, 0, stream>>>(Wg, Wl, pWg, pWl, bcnt);
    k_mega<<<GB + PA_NB, 256, 0, stream>>>(x, pWg, attn_l, attn_r, feat2, el, er,
                                           src, dst, bcnt, pairs);
    k_agg64<<<AGB, 1024, 0, stream>>>(pairs, bcnt, el, er, feat2, bias,
                                      pWl, out);
}